// Round 21
// baseline (160.747 us; speedup 1.0000x reference)
//
#include <hip/hip_runtime.h>
#include <stdint.h>

#define Bb 4
#define Tt 2048
#define Dd 1024
#define Hh 16
#define HDd 64
#define Mm 8192   // Bb*Tt

typedef __attribute__((ext_vector_type(8))) short bf16x8;
typedef __attribute__((ext_vector_type(4))) float f32x4;
typedef __attribute__((ext_vector_type(16))) float f32x16;

#define MFMA(a, b, c) __builtin_amdgcn_mfma_f32_16x16x32_bf16(a, b, c, 0, 0, 0)
#define MFMA32(a, b, c) __builtin_amdgcn_mfma_f32_32x32x16_bf16(a, b, c, 0, 0, 0)

#define LOG2E 1.44269504088896340736f
#if __has_builtin(__builtin_amdgcn_exp2f)
#define EXP2(x) __builtin_amdgcn_exp2f(x)
#else
#define EXP2(x) __expf((x) * 0.69314718055994530942f)
#endif

union vfu { uint2 u2[2]; bf16x8 v; };
union apu { uint32_t u[4]; bf16x8 v; };

__device__ __forceinline__ unsigned short f2b(float f) {
  union { float f; uint32_t u; } v; v.f = f;
  return (unsigned short)((v.u + 0x7FFFu + ((v.u >> 16) & 1u)) >> 16);
}

// pack two f32 -> bf16x2 (compiler emits v_cvt_pk_bf16_f32)
__device__ __forceinline__ uint32_t pk2(float a, float b) {
  union { __bf16 h[2]; uint32_t u; } x;
  x.h[0] = (__bf16)a; x.h[1] = (__bf16)b;
  return x.u;
}

__device__ __forceinline__ void gload_lds16(const void* g, void* l) {
  __builtin_amdgcn_global_load_lds(
      (const __attribute__((address_space(1))) void*)g,
      (__attribute__((address_space(3))) void*)l, 16, 0, 0);
}

// ---------------- x f32 -> bf16 ----------------
__global__ __launch_bounds__(256) void k_convert_x(const float* __restrict__ x,
                                                   unsigned short* __restrict__ xb) {
  int i = (blockIdx.x * 256 + threadIdx.x) * 8;
  float4 a = *(const float4*)(x + i);
  float4 b = *(const float4*)(x + i + 4);
  uint4 o;
  o.x = f2b(a.x) | ((uint32_t)f2b(a.y) << 16);
  o.y = f2b(a.z) | ((uint32_t)f2b(a.w) << 16);
  o.z = f2b(b.x) | ((uint32_t)f2b(b.y) << 16);
  o.w = f2b(b.z) | ((uint32_t)f2b(b.w) << 16);
  *(uint4*)(xb + i) = o;
}

// ---------------- W [K][N] f32 -> Wt [N][K] bf16 ----------------
__global__ __launch_bounds__(256) void k_transpose_w(
    const float* __restrict__ Wk, const float* __restrict__ Wq,
    const float* __restrict__ Wv, const float* __restrict__ Wp,
    unsigned short* __restrict__ WkT, unsigned short* __restrict__ WqT,
    unsigned short* __restrict__ WvT, unsigned short* __restrict__ WpT) {
  const float* W; unsigned short* O;
  int wsel = blockIdx.y;
  W = wsel == 0 ? Wk : wsel == 1 ? Wq : wsel == 2 ? Wv : Wp;
  O = wsel == 0 ? WkT : wsel == 1 ? WqT : wsel == 2 ? WvT : WpT;
  __shared__ unsigned short tile[32][36];
  int kb = (blockIdx.x >> 5) << 5;
  int nb = (blockIdx.x & 31) << 5;
  int t = threadIdx.x;
  int r = t >> 3, c4 = (t & 7) << 2;
  float4 v = *(const float4*)(W + (size_t)(kb + r) * Dd + nb + c4);
  tile[r][c4 + 0] = f2b(v.x); tile[r][c4 + 1] = f2b(v.y);
  tile[r][c4 + 2] = f2b(v.z); tile[r][c4 + 3] = f2b(v.w);
  __syncthreads();
  uint2 o;
  o.x = tile[c4 + 0][r] | ((uint32_t)tile[c4 + 1][r] << 16);
  o.y = tile[c4 + 2][r] | ((uint32_t)tile[c4 + 3][r] << 16);
  *(uint2*)(O + (size_t)(nb + r) * Dd + kb + c4) = o;
}

// ---------------- fused QKV GEMM: xb @ {Wq,Wk,Wv}^T + bias ----------------
// NOW double-buffered (attn's proven schedule): stage(k+1) issues before
// compute(k); one barrier per K-step. LDS 2 x (8K A + 24K B) = 64 KB.
__global__ __launch_bounds__(256, 2) void k_gemm3(
    const unsigned short* __restrict__ A,
    const unsigned short* __restrict__ BtQ, const unsigned short* __restrict__ BtK,
    const unsigned short* __restrict__ BtV,
    const float* __restrict__ bq, const float* __restrict__ bk,
    const float* __restrict__ bv,
    unsigned short* __restrict__ Qb, unsigned short* __restrict__ Kb,
    unsigned short* __restrict__ VTb) {
  __shared__ __align__(16) unsigned short Al[2][128 * 32];
  __shared__ __align__(16) unsigned short Bl[2][3][128 * 32];
  int tid = threadIdx.x;
  int lane = tid & 63, wid = tid >> 6;
  int wr = wid >> 1, wc = wid & 1;
  int lq = lane & 15, lh = lane >> 4;
  int mb = blockIdx.x * 128;
  int nb = blockIdx.y << 7;

  int srow = (wid << 5) + (lane >> 2);
  int scol = (lane & 3) << 3;
  const unsigned short* Ag = A + (size_t)(mb + srow) * Dd + scol;
  const unsigned short* Bg0 = BtQ + (size_t)(nb + srow) * Dd + scol;
  const unsigned short* Bg1 = BtK + (size_t)(nb + srow) * Dd + scol;
  const unsigned short* Bg2 = BtV + (size_t)(nb + srow) * Dd + scol;
  int lofs = wid << 10;   // wave-uniform LDS offset (wid*32 rows * 32 elems)

#define STAGE3(kb_, bi_) do {                                            \
    gload_lds16(Ag + (kb_), &Al[bi_][0] + lofs);                         \
    gload_lds16(Ag + (kb_) + 16 * Dd, &Al[bi_][0] + lofs + 16 * 32);     \
    gload_lds16(Bg0 + (kb_), &Bl[bi_][0][0] + lofs);                     \
    gload_lds16(Bg0 + (kb_) + 16 * Dd, &Bl[bi_][0][0] + lofs + 16 * 32); \
    gload_lds16(Bg1 + (kb_), &Bl[bi_][1][0] + lofs);                     \
    gload_lds16(Bg1 + (kb_) + 16 * Dd, &Bl[bi_][1][0] + lofs + 16 * 32); \
    gload_lds16(Bg2 + (kb_), &Bl[bi_][2][0] + lofs);                     \
    gload_lds16(Bg2 + (kb_) + 16 * Dd, &Bl[bi_][2][0] + lofs + 16 * 32); \
  } while (0)

  f32x4 zero = {0.f, 0.f, 0.f, 0.f};
  f32x4 acc[3][4][4];
#pragma unroll
  for (int s = 0; s < 3; s++)
#pragma unroll
    for (int m = 0; m < 4; m++)
#pragma unroll
      for (int n = 0; n < 4; n++) acc[s][m][n] = zero;

  STAGE3(0, 0);
  __syncthreads();

  int cur = 0;
  for (int kb = 0; kb < Dd; kb += 32) {
    if (kb + 32 < Dd) STAGE3(kb + 32, cur ^ 1);   // hides under compute(kb)
    bf16x8 af[4];
#pragma unroll
    for (int m = 0; m < 4; m++)
      af[m] = *(const bf16x8*)(&Al[cur][0] +
                               (((wr << 6) + (m << 4) + lq) << 5) + (lh << 3));
#pragma unroll
    for (int s = 0; s < 3; s++) {
      bf16x8 bf[4];
#pragma unroll
      for (int n = 0; n < 4; n++)
        bf[n] = *(const bf16x8*)(&Bl[cur][s][0] +
                                 (((wc << 6) + (n << 4) + lq) << 5) + (lh << 3));
      __builtin_amdgcn_s_setprio(1);
#pragma unroll
      for (int m = 0; m < 4; m++)
#pragma unroll
        for (int n = 0; n < 4; n++) acc[s][m][n] = MFMA(af[m], bf[n], acc[s][m][n]);
      __builtin_amdgcn_s_setprio(0);
    }
    __syncthreads();   // drains this iter's staging; joins readers of cur
    cur ^= 1;
  }
#undef STAGE3

  int b_idx = mb >> 11;
#pragma unroll
  for (int s = 0; s < 3; s++) {
#pragma unroll
    for (int n = 0; n < 4; n++) {
      int col = nb + (wc << 6) + (n << 4) + lq;
      float bbias = (s == 0) ? bq[col] : (s == 1) ? bk[col] : bv[col];
      int hh = col >> 6, hd = col & 63;
#pragma unroll
      for (int m = 0; m < 4; m++) {
        int row0 = mb + (wr << 6) + (m << 4) + (lh << 2);
        int t0 = row0 & 2047;
        if (s == 2) {          // V -> [B,H,64,T], t-swizzled
          float v0 = acc[s][m][n][0] + bbias, v1 = acc[s][m][n][1] + bbias;
          float v2 = acc[s][m][n][2] + bbias, v3 = acc[s][m][n][3] + bbias;
          uint2 pv;
          pv.x = f2b(v0) | ((uint32_t)f2b(v1) << 16);
          pv.y = f2b(v2) | ((uint32_t)f2b(v3) << 16);
          int t0s = t0 ^ ((hd & 7) << 3);
          *(uint2*)(VTb + ((size_t)(b_idx * 16 + hh) * 64 + hd) * Tt + t0s) = pv;
        } else {               // Q (scaled) / K (row-swizzled) -> [B,H,T,64]
          unsigned short* O = (s == 0) ? Qb : Kb;
          float sc = (s == 0) ? (0.125f * LOG2E) : 1.0f;
#pragma unroll
          for (int r = 0; r < 4; r++) {
            float v = (acc[s][m][n][r] + bbias) * sc;
            int trow = t0 + r;
            int hds = (s == 0) ? hd : (hd ^ ((trow & 7) << 3));
            O[((size_t)(b_idx * 16 + hh) * Tt + trow) * 64 + hds] = f2b(v);
          }
        }
      }
    }
  }
}

// ---------------- GEMM (projection): A[M][1024] bf16 @ Bt^T + bias -> f32 ----
// Double-buffered staging (same schedule as gemm3/attn). LDS 32 KB.
__global__ __launch_bounds__(256) void k_gemm(
    const unsigned short* __restrict__ A,
    const unsigned short* __restrict__ Bt0,
    const float* __restrict__ bias0,
    float* __restrict__ Pout) {
  __shared__ __align__(16) unsigned short Al[2][128 * 32];
  __shared__ __align__(16) unsigned short Bl[2][128 * 32];
  int tid = threadIdx.x;
  int lane = tid & 63, wid = tid >> 6;
  int wr = wid >> 1, wc = wid & 1;
  int lq = lane & 15, lh = lane >> 4;
  int mb = blockIdx.x * 128;
  int nb = blockIdx.y << 7;

  int srow = (wid << 5) + (lane >> 2);
  int scol = (lane & 3) << 3;
  const unsigned short* Ag = A + (size_t)(mb + srow) * Dd + scol;
  const unsigned short* Bg = Bt0 + (size_t)(nb + srow) * Dd + scol;
  int lofs = wid << 10;

#define STAGEP(kb_, bi_) do {                                            \
    gload_lds16(Ag + (kb_), &Al[bi_][0] + lofs);                         \
    gload_lds16(Ag + (kb_) + 16 * Dd, &Al[bi_][0] + lofs + 16 * 32);     \
    gload_lds16(Bg + (kb_), &Bl[bi_][0] + lofs);                         \
    gload_lds16(Bg + (kb_) + 16 * Dd, &Bl[bi_][0] + lofs + 16 * 32);     \
  } while (0)

  f32x4 zero = {0.f, 0.f, 0.f, 0.f};
  f32x4 acc[4][4];
#pragma unroll
  for (int m = 0; m < 4; m++)
#pragma unroll
    for (int n = 0; n < 4; n++) acc[m][n] = zero;

  STAGEP(0, 0);
  __syncthreads();

  int cur = 0;
  for (int kb = 0; kb < Dd; kb += 32) {
    if (kb + 32 < Dd) STAGEP(kb + 32, cur ^ 1);
    bf16x8 af[4], bf[4];
#pragma unroll
    for (int m = 0; m < 4; m++)
      af[m] = *(const bf16x8*)(&Al[cur][0] +
                               (((wr << 6) + (m << 4) + lq) << 5) + (lh << 3));
#pragma unroll
    for (int n = 0; n < 4; n++)
      bf[n] = *(const bf16x8*)(&Bl[cur][0] +
                               (((wc << 6) + (n << 4) + lq) << 5) + (lh << 3));
    __builtin_amdgcn_s_setprio(1);
#pragma unroll
    for (int m = 0; m < 4; m++)
#pragma unroll
      for (int n = 0; n < 4; n++) acc[m][n] = MFMA(af[m], bf[n], acc[m][n]);
    __builtin_amdgcn_s_setprio(0);
    __syncthreads();
    cur ^= 1;
  }
#undef STAGEP

#pragma unroll
  for (int n = 0; n < 4; n++) {
    int col = nb + (wc << 6) + (n << 4) + lq;
    float bb = bias0[col];
#pragma unroll
    for (int m = 0; m < 4; m++) {
      int row0 = mb + (wr << 6) + (m << 4) + (lh << 2);
#pragma unroll
      for (int r = 0; r < 4; r++)
        Pout[(size_t)(row0 + r) * Dd + col] = acc[m][n][r] + bb;
    }
  }
}

// ---------------- flash attention (causal), Q pre-scaled by 0.125*log2e ----------
// r20 attn unchanged: 128-row KV tiles, double-buffered staging, lsum via
// ones-MFMA, fully-masked A-half sub-blocks skipped.
__global__ __launch_bounds__(256, 2) void k_attn(
    const unsigned short* __restrict__ Qb, const unsigned short* __restrict__ Kb,
    const unsigned short* __restrict__ VTb, unsigned short* __restrict__ yb) {
  __shared__ __align__(16) unsigned short KL[2][8192];  // 128 kv rows x 64 hd
  __shared__ __align__(16) unsigned short VL[2][8192];  // 64 hd rows x 128 t
  int b = blockIdx.x;
  int qt = (b < 256) ? (7 - (b >> 6)) : ((b - 256) >> 6);
  int rr6 = b & 63;
  int bh = ((rr6 & 7) << 3) | (rr6 >> 3);    // XCD x holds heads 8x..8x+7
  int tid = threadIdx.x, lane = tid & 63, w = tid >> 6;
  int l31 = lane & 31, hi = lane >> 5;
  const unsigned short* __restrict__ Qh = Qb + (size_t)bh * Tt * 64;
  const unsigned short* __restrict__ Kh = Kb + (size_t)bh * Tt * 64;
  const unsigned short* __restrict__ Vh = VTb + (size_t)bh * 64 * Tt;
  int qgA = (qt << 8) + (w << 6);            // wave's 64 q rows (two halves)
  int qgB = qgA + 32;

  bf16x8 qfA[4], qfB[4];
#pragma unroll
  for (int c = 0; c < 4; c++) {
    qfA[c] = *(const bf16x8*)(Qh + (size_t)(qgA + l31) * 64 + (c << 4) + (hi << 3));
    qfB[c] = *(const bf16x8*)(Qh + (size_t)(qgB + l31) * 64 + (c << 4) + (hi << 3));
  }

  f32x16 accA0, accA1, accB0, accB1, accLA, accLB;
#pragma unroll
  for (int i = 0; i < 16; i++) {
    accA0[i] = 0.f; accA1[i] = 0.f; accB0[i] = 0.f; accB1[i] = 0.f;
    accLA[i] = 0.f; accLB[i] = 0.f;
  }
  apu onesf;
  onesf.u[0] = onesf.u[1] = onesf.u[2] = onesf.u[3] = 0x3F803F80u;  // bf16 1.0 x8

  int jmaxb = (qt << 1) + 1;   // 128-row kv tiles: 0..jmaxb covers q-tile diag
  int srowK = lane >> 3, scolK = (lane & 7) << 3;
  int rowbK = w << 5;          // wave stages 32 K rows per tile
  int srowV = lane >> 4, scolV = (lane & 15) << 3;
  int rowbV = w << 4;          // wave stages 16 V rows (x128 t) per tile
  int swz = l31 & 7;

#define STAGE(kvt_, bi_) do {                                                        \
    int kv_ = (kvt_) << 7;                                                           \
    gload_lds16(Kh + (size_t)(kv_ + rowbK + srowK) * 64 + scolK,                     \
                &KL[bi_][rowbK << 6]);                                               \
    gload_lds16(Kh + (size_t)(kv_ + rowbK + 8 + srowK) * 64 + scolK,                 \
                &KL[bi_][(rowbK + 8) << 6]);                                         \
    gload_lds16(Kh + (size_t)(kv_ + rowbK + 16 + srowK) * 64 + scolK,                \
                &KL[bi_][(rowbK + 16) << 6]);                                        \
    gload_lds16(Kh + (size_t)(kv_ + rowbK + 24 + srowK) * 64 + scolK,                \
                &KL[bi_][(rowbK + 24) << 6]);                                        \
    gload_lds16(Vh + (size_t)(rowbV + srowV) * Tt + kv_ + scolV,                     \
                &VL[bi_][rowbV << 7]);                                               \
    gload_lds16(Vh + (size_t)(rowbV + 4 + srowV) * Tt + kv_ + scolV,                 \
                &VL[bi_][(rowbV + 4) << 7]);                                         \
    gload_lds16(Vh + (size_t)(rowbV + 8 + srowV) * Tt + kv_ + scolV,                 \
                &VL[bi_][(rowbV + 8) << 7]);                                         \
    gload_lds16(Vh + (size_t)(rowbV + 12 + srowV) * Tt + kv_ + scolV,                \
                &VL[bi_][(rowbV + 12) << 7]);                                        \
  } while (0)

  STAGE(0, 0);
  __syncthreads();

  int cur = 0;
  for (int jt = 0; jt <= jmaxb; ++jt) {
    if (jt < jmaxb) STAGE(jt + 1, cur ^ 1);  // latency hides under 2x compute
    int base_kv = jt << 7;
    if (qgB >= base_kv) {
      const unsigned short* KB = &KL[cur][0];
      const unsigned short* VB = &VL[cur][0];
#pragma unroll
      for (int n2 = 0; n2 < 4; n2++) {
        int rel_base = qgA - base_kv - (n2 << 5);   // wave-uniform, mult of 32
        if (rel_base >= -32) {                      // B-half has unmasked rows
          bool doA = (rel_base >= 0);               // A-half not fully masked
          bf16x8 kf[4];
          int krowb = ((n2 << 5) + l31) << 6;
#pragma unroll
          for (int c = 0; c < 4; c++)
            kf[c] = *(const bf16x8*)(KB + krowb + ((((c << 1) + hi) ^ swz) << 3));
          f32x16 sA, sB;
#pragma unroll
          for (int i = 0; i < 16; i++) { sA[i] = 0.f; sB[i] = 0.f; }
          __builtin_amdgcn_s_setprio(1);
          if (doA) {
#pragma unroll
            for (int c = 0; c < 4; c++) {
              sA = MFMA32(kf[c], qfA[c], sA);
              sB = MFMA32(kf[c], qfB[c], sB);
            }
          } else {
#pragma unroll
            for (int c = 0; c < 4; c++) sB = MFMA32(kf[c], qfB[c], sB);
          }
          __builtin_amdgcn_s_setprio(0);
          float pA[16], pB[16];
          if (rel_base <= 0) {   // diagonal region
            int relA = rel_base + l31, relB = relA + 32;
#pragma unroll
            for (int r = 0; r < 16; r++) {
              int krow = (r & 3) + ((r >> 2) << 3) + (hi << 2);
              if (doA) pA[r] = EXP2(krow > relA ? -1e30f : sA[r]);
              pB[r] = EXP2(krow > relB ? -1e30f : sB[r]);
            }
          } else {
#pragma unroll
            for (int r = 0; r < 16; r++) { pA[r] = EXP2(sA[r]); pB[r] = EXP2(sB[r]); }
          }
          vfu vf[2][2];
#pragma unroll
          for (int n2v = 0; n2v < 2; n2v++) {
            int vrowb = ((n2v << 5) + l31) << 7;   // V row stride = 128 t
#pragma unroll
            for (int cc = 0; cc < 2; cc++) {
              int blk0 = (n2 << 2) + (cc << 1);    // t-block in [0,15]
              vf[n2v][cc].u2[0] =
                  *(const uint2*)(VB + vrowb + ((blk0 ^ swz) << 3) + (hi << 2));
              vf[n2v][cc].u2[1] =
                  *(const uint2*)(VB + vrowb + (((blk0 + 1) ^ swz) << 3) + (hi << 2));
            }
          }
          apu b0, b1;
#pragma unroll
          for (int g = 0; g < 4; g++) {
            b0.u[g] = pk2(pB[2 * g], pB[2 * g + 1]);
            b1.u[g] = pk2(pB[8 + 2 * g], pB[8 + 2 * g + 1]);
          }
          __builtin_amdgcn_s_setprio(1);
          accB0 = MFMA32(b0.v, vf[0][0].v, accB0);
          accB1 = MFMA32(b0.v, vf[1][0].v, accB1);
          accLB = MFMA32(b0.v, onesf.v, accLB);
          accB0 = MFMA32(b1.v, vf[0][1].v, accB0);
          accB1 = MFMA32(b1.v, vf[1][1].v, accB1);
          accLB = MFMA32(b1.v, onesf.v, accLB);
          __builtin_amdgcn_s_setprio(0);
          if (doA) {
            apu a0, a1;
#pragma unroll
            for (int g = 0; g < 4; g++) {
              a0.u[g] = pk2(pA[2 * g], pA[2 * g + 1]);
              a1.u[g] = pk2(pA[8 + 2 * g], pA[8 + 2 * g + 1]);
            }
            __builtin_amdgcn_s_setprio(1);
            accA0 = MFMA32(a0.v, vf[0][0].v, accA0);
            accA1 = MFMA32(a0.v, vf[1][0].v, accA1);
            accLA = MFMA32(a0.v, onesf.v, accLA);
            accA0 = MFMA32(a1.v, vf[0][1].v, accA0);
            accA1 = MFMA32(a1.v, vf[1][1].v, accA1);
            accLA = MFMA32(a1.v, onesf.v, accLA);
            __builtin_amdgcn_s_setprio(0);
          }
        }
      }
    }
    __syncthreads();
    cur ^= 1;
  }
#undef STAGE

  // accL[r] = lsum for q = crow(r,hi) -- same indexing as accA/accB rows.
  int bb = bh >> 4, hh = bh & 15;
#pragma unroll
  for (int r = 0; r < 16; r++) {
    int qr = (r & 3) + ((r >> 2) << 3) + (hi << 2);
    float invqA = 1.0f / accLA[r];
    float invqB = 1.0f / accLB[r];
    size_t baseA = ((size_t)(bb * Tt + qgA + qr)) * Dd + (hh << 6) + l31;
    size_t baseB = ((size_t)(bb * Tt + qgB + qr)) * Dd + (hh << 6) + l31;
    yb[baseA] = f2b(accA0[r] * invqA);
    yb[baseA + 32] = f2b(accA1[r] * invqA);
    yb[baseB] = f2b(accB0[r] * invqB);
    yb[baseB + 32] = f2b(accB1[r] * invqB);
  }
}

extern "C" void kernel_launch(void* const* d_in, const int* in_sizes, int n_in,
                              void* d_out, int out_size, void* d_ws, size_t ws_size,
                              hipStream_t stream) {
  const float* x = (const float*)d_in[0];
  const float* Wk = (const float*)d_in[1];
  const float* bk = (const float*)d_in[2];
  const float* Wq = (const float*)d_in[3];
  const float* bq = (const float*)d_in[4];
  const float* Wv = (const float*)d_in[5];
  const float* bv = (const float*)d_in[6];
  const float* Wp = (const float*)d_in[7];
  const float* bp = (const float*)d_in[8];
  float* out = (float*)d_out;

  char* ws = (char*)d_ws;
  unsigned short* xb  = (unsigned short*)(ws);                       // 16MB
  unsigned short* WkT = (unsigned short*)(ws + (16ull << 20));       // 2MB each
  unsigned short* WqT = (unsigned short*)(ws + (18ull << 20));
  unsigned short* WvT = (unsigned short*)(ws + (20ull << 20));
  unsigned short* WpT = (unsigned short*)(ws + (22ull << 20));
  unsigned short* Qb  = (unsigned short*)(ws + (24ull << 20));       // 16MB
  unsigned short* Kb  = (unsigned short*)(ws + (40ull << 20));       // 16MB
  unsigned short* VTb = (unsigned short*)(ws + (56ull << 20));       // 16MB
  unsigned short* yb  = (unsigned short*)(ws + (72ull << 20));       // 16MB (ends 88MB)

  k_convert_x<<<4096, 256, 0, stream>>>(x, xb);
  k_transpose_w<<<dim3(1024, 4), 256, 0, stream>>>(Wk, Wq, Wv, Wp, WkT, WqT, WvT, WpT);
  k_gemm3<<<dim3(64, 8), 256, 0, stream>>>(xb, WqT, WkT, WvT, bq, bk, bv,
                                           Qb, Kb, VTb);
  k_attn<<<512, 256, 0, stream>>>(Qb, Kb, VTb, yb);
  k_gemm<<<dim3(64, 8), 256, 0, stream>>>(yb, WpT, bp, out);
}

// Round 22
// 153.582 us; speedup vs baseline: 1.0466x; 1.0466x over previous
//
#include <hip/hip_runtime.h>
#include <stdint.h>

#define Bb 4
#define Tt 2048
#define Dd 1024
#define Hh 16
#define HDd 64
#define Mm 8192   // Bb*Tt

typedef __attribute__((ext_vector_type(8))) short bf16x8;
typedef __attribute__((ext_vector_type(4))) float f32x4;
typedef __attribute__((ext_vector_type(16))) float f32x16;

#define MFMA(a, b, c) __builtin_amdgcn_mfma_f32_16x16x32_bf16(a, b, c, 0, 0, 0)
#define MFMA32(a, b, c) __builtin_amdgcn_mfma_f32_32x32x16_bf16(a, b, c, 0, 0, 0)

#define LOG2E 1.44269504088896340736f
#if __has_builtin(__builtin_amdgcn_exp2f)
#define EXP2(x) __builtin_amdgcn_exp2f(x)
#else
#define EXP2(x) __expf((x) * 0.69314718055994530942f)
#endif

union vfu { uint2 u2[2]; bf16x8 v; };
union apu { uint32_t u[4]; bf16x8 v; };

__device__ __forceinline__ unsigned short f2b(float f) {
  union { float f; uint32_t u; } v; v.f = f;
  return (unsigned short)((v.u + 0x7FFFu + ((v.u >> 16) & 1u)) >> 16);
}

// pack two f32 -> bf16x2 (compiler emits v_cvt_pk_bf16_f32)
__device__ __forceinline__ uint32_t pk2(float a, float b) {
  union { __bf16 h[2]; uint32_t u; } x;
  x.h[0] = (__bf16)a; x.h[1] = (__bf16)b;
  return x.u;
}

__device__ __forceinline__ void gload_lds16(const void* g, void* l) {
  __builtin_amdgcn_global_load_lds(
      (const __attribute__((address_space(1))) void*)g,
      (__attribute__((address_space(3))) void*)l, 16, 0, 0);
}

// ---------------- x f32 -> bf16 ----------------
__global__ __launch_bounds__(256) void k_convert_x(const float* __restrict__ x,
                                                   unsigned short* __restrict__ xb) {
  int i = (blockIdx.x * 256 + threadIdx.x) * 8;
  float4 a = *(const float4*)(x + i);
  float4 b = *(const float4*)(x + i + 4);
  uint4 o;
  o.x = f2b(a.x) | ((uint32_t)f2b(a.y) << 16);
  o.y = f2b(a.z) | ((uint32_t)f2b(a.w) << 16);
  o.z = f2b(b.x) | ((uint32_t)f2b(b.y) << 16);
  o.w = f2b(b.z) | ((uint32_t)f2b(b.w) << 16);
  *(uint4*)(xb + i) = o;
}

// ---------------- W [K][N] f32 -> Wt [N][K] bf16 ----------------
__global__ __launch_bounds__(256) void k_transpose_w(
    const float* __restrict__ Wk, const float* __restrict__ Wq,
    const float* __restrict__ Wv, const float* __restrict__ Wp,
    unsigned short* __restrict__ WkT, unsigned short* __restrict__ WqT,
    unsigned short* __restrict__ WvT, unsigned short* __restrict__ WpT) {
  const float* W; unsigned short* O;
  int wsel = blockIdx.y;
  W = wsel == 0 ? Wk : wsel == 1 ? Wq : wsel == 2 ? Wv : Wp;
  O = wsel == 0 ? WkT : wsel == 1 ? WqT : wsel == 2 ? WvT : WpT;
  __shared__ unsigned short tile[32][36];
  int kb = (blockIdx.x >> 5) << 5;
  int nb = (blockIdx.x & 31) << 5;
  int t = threadIdx.x;
  int r = t >> 3, c4 = (t & 7) << 2;
  float4 v = *(const float4*)(W + (size_t)(kb + r) * Dd + nb + c4);
  tile[r][c4 + 0] = f2b(v.x); tile[r][c4 + 1] = f2b(v.y);
  tile[r][c4 + 2] = f2b(v.z); tile[r][c4 + 3] = f2b(v.w);
  __syncthreads();
  uint2 o;
  o.x = tile[c4 + 0][r] | ((uint32_t)tile[c4 + 1][r] << 16);
  o.y = tile[c4 + 2][r] | ((uint32_t)tile[c4 + 3][r] << 16);
  *(uint2*)(O + (size_t)(nb + r) * Dd + kb + c4) = o;
}

// ---------------- fused QKV GEMM: xb @ {Wq,Wk,Wv}^T + bias ----------------
// Double-buffered staging (neutral vs serial, kept). LDS 64 KB.
__global__ __launch_bounds__(256, 2) void k_gemm3(
    const unsigned short* __restrict__ A,
    const unsigned short* __restrict__ BtQ, const unsigned short* __restrict__ BtK,
    const unsigned short* __restrict__ BtV,
    const float* __restrict__ bq, const float* __restrict__ bk,
    const float* __restrict__ bv,
    unsigned short* __restrict__ Qb, unsigned short* __restrict__ Kb,
    unsigned short* __restrict__ VTb) {
  __shared__ __align__(16) unsigned short Al[2][128 * 32];
  __shared__ __align__(16) unsigned short Bl[2][3][128 * 32];
  int tid = threadIdx.x;
  int lane = tid & 63, wid = tid >> 6;
  int wr = wid >> 1, wc = wid & 1;
  int lq = lane & 15, lh = lane >> 4;
  int mb = blockIdx.x * 128;
  int nb = blockIdx.y << 7;

  int srow = (wid << 5) + (lane >> 2);
  int scol = (lane & 3) << 3;
  const unsigned short* Ag = A + (size_t)(mb + srow) * Dd + scol;
  const unsigned short* Bg0 = BtQ + (size_t)(nb + srow) * Dd + scol;
  const unsigned short* Bg1 = BtK + (size_t)(nb + srow) * Dd + scol;
  const unsigned short* Bg2 = BtV + (size_t)(nb + srow) * Dd + scol;
  int lofs = wid << 10;   // wave-uniform LDS offset (wid*32 rows * 32 elems)

#define STAGE3(kb_, bi_) do {                                            \
    gload_lds16(Ag + (kb_), &Al[bi_][0] + lofs);                         \
    gload_lds16(Ag + (kb_) + 16 * Dd, &Al[bi_][0] + lofs + 16 * 32);     \
    gload_lds16(Bg0 + (kb_), &Bl[bi_][0][0] + lofs);                     \
    gload_lds16(Bg0 + (kb_) + 16 * Dd, &Bl[bi_][0][0] + lofs + 16 * 32); \
    gload_lds16(Bg1 + (kb_), &Bl[bi_][1][0] + lofs);                     \
    gload_lds16(Bg1 + (kb_) + 16 * Dd, &Bl[bi_][1][0] + lofs + 16 * 32); \
    gload_lds16(Bg2 + (kb_), &Bl[bi_][2][0] + lofs);                     \
    gload_lds16(Bg2 + (kb_) + 16 * Dd, &Bl[bi_][2][0] + lofs + 16 * 32); \
  } while (0)

  f32x4 zero = {0.f, 0.f, 0.f, 0.f};
  f32x4 acc[3][4][4];
#pragma unroll
  for (int s = 0; s < 3; s++)
#pragma unroll
    for (int m = 0; m < 4; m++)
#pragma unroll
      for (int n = 0; n < 4; n++) acc[s][m][n] = zero;

  STAGE3(0, 0);
  __syncthreads();

  int cur = 0;
  for (int kb = 0; kb < Dd; kb += 32) {
    if (kb + 32 < Dd) STAGE3(kb + 32, cur ^ 1);   // hides under compute(kb)
    bf16x8 af[4];
#pragma unroll
    for (int m = 0; m < 4; m++)
      af[m] = *(const bf16x8*)(&Al[cur][0] +
                               (((wr << 6) + (m << 4) + lq) << 5) + (lh << 3));
#pragma unroll
    for (int s = 0; s < 3; s++) {
      bf16x8 bf[4];
#pragma unroll
      for (int n = 0; n < 4; n++)
        bf[n] = *(const bf16x8*)(&Bl[cur][s][0] +
                                 (((wc << 6) + (n << 4) + lq) << 5) + (lh << 3));
      __builtin_amdgcn_s_setprio(1);
#pragma unroll
      for (int m = 0; m < 4; m++)
#pragma unroll
        for (int n = 0; n < 4; n++) acc[s][m][n] = MFMA(af[m], bf[n], acc[s][m][n]);
      __builtin_amdgcn_s_setprio(0);
    }
    __syncthreads();   // drains this iter's staging; joins readers of cur
    cur ^= 1;
  }
#undef STAGE3

  int b_idx = mb >> 11;
#pragma unroll
  for (int s = 0; s < 3; s++) {
#pragma unroll
    for (int n = 0; n < 4; n++) {
      int col = nb + (wc << 6) + (n << 4) + lq;
      float bbias = (s == 0) ? bq[col] : (s == 1) ? bk[col] : bv[col];
      int hh = col >> 6, hd = col & 63;
#pragma unroll
      for (int m = 0; m < 4; m++) {
        int row0 = mb + (wr << 6) + (m << 4) + (lh << 2);
        int t0 = row0 & 2047;
        if (s == 2) {          // V -> [B,H,64,T], t-swizzled
          float v0 = acc[s][m][n][0] + bbias, v1 = acc[s][m][n][1] + bbias;
          float v2 = acc[s][m][n][2] + bbias, v3 = acc[s][m][n][3] + bbias;
          uint2 pv;
          pv.x = f2b(v0) | ((uint32_t)f2b(v1) << 16);
          pv.y = f2b(v2) | ((uint32_t)f2b(v3) << 16);
          int t0s = t0 ^ ((hd & 7) << 3);
          *(uint2*)(VTb + ((size_t)(b_idx * 16 + hh) * 64 + hd) * Tt + t0s) = pv;
        } else {               // Q (scaled) / K (row-swizzled) -> [B,H,T,64]
          unsigned short* O = (s == 0) ? Qb : Kb;
          float sc = (s == 0) ? (0.125f * LOG2E) : 1.0f;
#pragma unroll
          for (int r = 0; r < 4; r++) {
            float v = (acc[s][m][n][r] + bbias) * sc;
            int trow = t0 + r;
            int hds = (s == 0) ? hd : (hd ^ ((trow & 7) << 3));
            O[((size_t)(b_idx * 16 + hh) * Tt + trow) * 64 + hds] = f2b(v);
          }
        }
      }
    }
  }
}

// ---------------- GEMM (projection): A[M][1024] bf16 @ Bt^T + bias -> f32 ----
__global__ __launch_bounds__(256) void k_gemm(
    const unsigned short* __restrict__ A,
    const unsigned short* __restrict__ Bt0,
    const float* __restrict__ bias0,
    float* __restrict__ Pout) {
  __shared__ __align__(16) unsigned short Al[2][128 * 32];
  __shared__ __align__(16) unsigned short Bl[2][128 * 32];
  int tid = threadIdx.x;
  int lane = tid & 63, wid = tid >> 6;
  int wr = wid >> 1, wc = wid & 1;
  int lq = lane & 15, lh = lane >> 4;
  int mb = blockIdx.x * 128;
  int nb = blockIdx.y << 7;

  int srow = (wid << 5) + (lane >> 2);
  int scol = (lane & 3) << 3;
  const unsigned short* Ag = A + (size_t)(mb + srow) * Dd + scol;
  const unsigned short* Bg = Bt0 + (size_t)(nb + srow) * Dd + scol;
  int lofs = wid << 10;

#define STAGEP(kb_, bi_) do {                                            \
    gload_lds16(Ag + (kb_), &Al[bi_][0] + lofs);                         \
    gload_lds16(Ag + (kb_) + 16 * Dd, &Al[bi_][0] + lofs + 16 * 32);     \
    gload_lds16(Bg + (kb_), &Bl[bi_][0] + lofs);                         \
    gload_lds16(Bg + (kb_) + 16 * Dd, &Bl[bi_][0] + lofs + 16 * 32);     \
  } while (0)

  f32x4 zero = {0.f, 0.f, 0.f, 0.f};
  f32x4 acc[4][4];
#pragma unroll
  for (int m = 0; m < 4; m++)
#pragma unroll
    for (int n = 0; n < 4; n++) acc[m][n] = zero;

  STAGEP(0, 0);
  __syncthreads();

  int cur = 0;
  for (int kb = 0; kb < Dd; kb += 32) {
    if (kb + 32 < Dd) STAGEP(kb + 32, cur ^ 1);
    bf16x8 af[4], bf[4];
#pragma unroll
    for (int m = 0; m < 4; m++)
      af[m] = *(const bf16x8*)(&Al[cur][0] +
                               (((wr << 6) + (m << 4) + lq) << 5) + (lh << 3));
#pragma unroll
    for (int n = 0; n < 4; n++)
      bf[n] = *(const bf16x8*)(&Bl[cur][0] +
                               (((wc << 6) + (n << 4) + lq) << 5) + (lh << 3));
    __builtin_amdgcn_s_setprio(1);
#pragma unroll
    for (int m = 0; m < 4; m++)
#pragma unroll
      for (int n = 0; n < 4; n++) acc[m][n] = MFMA(af[m], bf[n], acc[m][n]);
    __builtin_amdgcn_s_setprio(0);
    __syncthreads();
    cur ^= 1;
  }
#undef STAGEP

#pragma unroll
  for (int n = 0; n < 4; n++) {
    int col = nb + (wc << 6) + (n << 4) + lq;
    float bb = bias0[col];
#pragma unroll
    for (int m = 0; m < 4; m++) {
      int row0 = mb + (wr << 6) + (m << 4) + (lh << 2);
#pragma unroll
      for (int r = 0; r < 4; r++)
        Pout[(size_t)(row0 + r) * Dd + col] = acc[m][n][r] + bb;
    }
  }
}

// ---------------- flash attention (causal), Q pre-scaled by 0.125*log2e ----------
// UNIFORM-WORK pairing at the wave level: each wave owns 32 q-rows of a HEAVY
// 128-row q-tile (15-p) [B-half] and 32 q-rows of the complementary LIGHT tile
// (p) [A-half], sharing all staged K/V. Per-block compute = (p+1)*2 +
// (15-2p)*1 = 17 half-tile units, exactly uniform across all 512 blocks ->
// no triangular drain; every SIMD active to block end via its heavy half.
__global__ __launch_bounds__(256, 2) void k_attn(
    const unsigned short* __restrict__ Qb, const unsigned short* __restrict__ Kb,
    const unsigned short* __restrict__ VTb, unsigned short* __restrict__ yb) {
  __shared__ __align__(16) unsigned short KL[2][8192];  // 128 kv rows x 64 hd
  __shared__ __align__(16) unsigned short VL[2][8192];  // 64 hd rows x 128 t
  int b = blockIdx.x;
  int p = b >> 6;                            // 0..7 (heavy tile 15-p staged first)
  int rr6 = b & 63;
  int bh = ((rr6 & 7) << 3) | (rr6 >> 3);    // XCD x holds heads 8x..8x+7
  int tid = threadIdx.x, lane = tid & 63, w = tid >> 6;
  int l31 = lane & 31, hi = lane >> 5;
  const unsigned short* __restrict__ Qh = Qb + (size_t)bh * Tt * 64;
  const unsigned short* __restrict__ Kh = Kb + (size_t)bh * Tt * 64;
  const unsigned short* __restrict__ Vh = VTb + (size_t)bh * 64 * Tt;
  int qgA = (p << 7) + (w << 5);             // LIGHT half: tile p
  int qgB = ((15 - p) << 7) + (w << 5);      // HEAVY half: tile 15-p

  bf16x8 qfA[4], qfB[4];
#pragma unroll
  for (int c = 0; c < 4; c++) {
    qfA[c] = *(const bf16x8*)(Qh + (size_t)(qgA + l31) * 64 + (c << 4) + (hi << 3));
    qfB[c] = *(const bf16x8*)(Qh + (size_t)(qgB + l31) * 64 + (c << 4) + (hi << 3));
  }

  f32x16 accA0, accA1, accB0, accB1, accLA, accLB;
#pragma unroll
  for (int i = 0; i < 16; i++) {
    accA0[i] = 0.f; accA1[i] = 0.f; accB0[i] = 0.f; accB1[i] = 0.f;
    accLA[i] = 0.f; accLB[i] = 0.f;
  }
  apu onesf;
  onesf.u[0] = onesf.u[1] = onesf.u[2] = onesf.u[3] = 0x3F803F80u;  // bf16 1.0 x8

  int jmaxb = 15 - p;          // kv tiles (128 rows) needed by the heavy tile
  int srowK = lane >> 3, scolK = (lane & 7) << 3;
  int rowbK = w << 5;          // wave stages 32 K rows per tile
  int srowV = lane >> 4, scolV = (lane & 15) << 3;
  int rowbV = w << 4;          // wave stages 16 V rows (x128 t) per tile
  int swz = l31 & 7;

#define STAGE(kvt_, bi_) do {                                                        \
    int kv_ = (kvt_) << 7;                                                           \
    gload_lds16(Kh + (size_t)(kv_ + rowbK + srowK) * 64 + scolK,                     \
                &KL[bi_][rowbK << 6]);                                               \
    gload_lds16(Kh + (size_t)(kv_ + rowbK + 8 + srowK) * 64 + scolK,                 \
                &KL[bi_][(rowbK + 8) << 6]);                                         \
    gload_lds16(Kh + (size_t)(kv_ + rowbK + 16 + srowK) * 64 + scolK,                \
                &KL[bi_][(rowbK + 16) << 6]);                                        \
    gload_lds16(Kh + (size_t)(kv_ + rowbK + 24 + srowK) * 64 + scolK,                \
                &KL[bi_][(rowbK + 24) << 6]);                                        \
    gload_lds16(Vh + (size_t)(rowbV + srowV) * Tt + kv_ + scolV,                     \
                &VL[bi_][rowbV << 7]);                                               \
    gload_lds16(Vh + (size_t)(rowbV + 4 + srowV) * Tt + kv_ + scolV,                 \
                &VL[bi_][(rowbV + 4) << 7]);                                         \
    gload_lds16(Vh + (size_t)(rowbV + 8 + srowV) * Tt + kv_ + scolV,                 \
                &VL[bi_][(rowbV + 8) << 7]);                                         \
    gload_lds16(Vh + (size_t)(rowbV + 12 + srowV) * Tt + kv_ + scolV,                \
                &VL[bi_][(rowbV + 12) << 7]);                                        \
  } while (0)

  STAGE(0, 0);
  __syncthreads();

  int cur = 0;
  for (int jt = 0; jt <= jmaxb; ++jt) {
    if (jt < jmaxb) STAGE(jt + 1, cur ^ 1);  // latency hides under compute
    int base_kv = jt << 7;
    const unsigned short* KB = &KL[cur][0];
    const unsigned short* VB = &VL[cur][0];
#pragma unroll
    for (int n2 = 0; n2 < 4; n2++) {
      int relB = qgB - base_kv - (n2 << 5);   // heavy half, wave-uniform, mult 32
      int relA = qgA - base_kv - (n2 << 5);   // light half
      if (relB >= 0) {                        // heavy has unmasked rows
        bool doA = (relA >= 0);               // light not fully masked
        bf16x8 kf[4];
        int krowb = ((n2 << 5) + l31) << 6;
#pragma unroll
        for (int c = 0; c < 4; c++)
          kf[c] = *(const bf16x8*)(KB + krowb + ((((c << 1) + hi) ^ swz) << 3));
        f32x16 sA, sB;
#pragma unroll
        for (int i = 0; i < 16; i++) { sA[i] = 0.f; sB[i] = 0.f; }
        __builtin_amdgcn_s_setprio(1);
        if (doA) {
#pragma unroll
          for (int c = 0; c < 4; c++) {
            sA = MFMA32(kf[c], qfA[c], sA);
            sB = MFMA32(kf[c], qfB[c], sB);
          }
        } else {
#pragma unroll
          for (int c = 0; c < 4; c++) sB = MFMA32(kf[c], qfB[c], sB);
        }
        __builtin_amdgcn_s_setprio(0);
        float pA[16], pB[16];
        if (relB == 0) {       // heavy diagonal sub-block
          int rB = l31;        // relB + l31
#pragma unroll
          for (int r = 0; r < 16; r++) {
            int krow = (r & 3) + ((r >> 2) << 3) + (hi << 2);
            pB[r] = EXP2(krow > rB ? -1e30f : sB[r]);
          }
        } else {
#pragma unroll
          for (int r = 0; r < 16; r++) pB[r] = EXP2(sB[r]);
        }
        if (doA) {
          if (relA == 0) {     // light diagonal sub-block
            int rA = l31;
#pragma unroll
            for (int r = 0; r < 16; r++) {
              int krow = (r & 3) + ((r >> 2) << 3) + (hi << 2);
              pA[r] = EXP2(krow > rA ? -1e30f : sA[r]);
            }
          } else {
#pragma unroll
            for (int r = 0; r < 16; r++) pA[r] = EXP2(sA[r]);
          }
        }
        vfu vf[2][2];
#pragma unroll
        for (int n2v = 0; n2v < 2; n2v++) {
          int vrowb = ((n2v << 5) + l31) << 7;   // V row stride = 128 t
#pragma unroll
          for (int cc = 0; cc < 2; cc++) {
            int blk0 = (n2 << 2) + (cc << 1);    // t-block in [0,15]
            vf[n2v][cc].u2[0] =
                *(const uint2*)(VB + vrowb + ((blk0 ^ swz) << 3) + (hi << 2));
            vf[n2v][cc].u2[1] =
                *(const uint2*)(VB + vrowb + (((blk0 + 1) ^ swz) << 3) + (hi << 2));
          }
        }
        apu b0, b1;
#pragma unroll
        for (int g = 0; g < 4; g++) {
          b0.u[g] = pk2(pB[2 * g], pB[2 * g + 1]);
          b1.u[g] = pk2(pB[8 + 2 * g], pB[8 + 2 * g + 1]);
        }
        __builtin_amdgcn_s_setprio(1);
        accB0 = MFMA32(b0.v, vf[0][0].v, accB0);
        accB1 = MFMA32(b0.v, vf[1][0].v, accB1);
        accLB = MFMA32(b0.v, onesf.v, accLB);
        accB0 = MFMA32(b1.v, vf[0][1].v, accB0);
        accB1 = MFMA32(b1.v, vf[1][1].v, accB1);
        accLB = MFMA32(b1.v, onesf.v, accLB);
        __builtin_amdgcn_s_setprio(0);
        if (doA) {
          apu a0, a1;
#pragma unroll
          for (int g = 0; g < 4; g++) {
            a0.u[g] = pk2(pA[2 * g], pA[2 * g + 1]);
            a1.u[g] = pk2(pA[8 + 2 * g], pA[8 + 2 * g + 1]);
          }
          __builtin_amdgcn_s_setprio(1);
          accA0 = MFMA32(a0.v, vf[0][0].v, accA0);
          accA1 = MFMA32(a0.v, vf[1][0].v, accA1);
          accLA = MFMA32(a0.v, onesf.v, accLA);
          accA0 = MFMA32(a1.v, vf[0][1].v, accA0);
          accA1 = MFMA32(a1.v, vf[1][1].v, accA1);
          accLA = MFMA32(a1.v, onesf.v, accLA);
          __builtin_amdgcn_s_setprio(0);
        }
      }
    }
    __syncthreads();
    cur ^= 1;
  }
#undef STAGE

  // accL[r] = lsum for q = crow(r,hi) -- same indexing as accA/accB rows.
  int bb = bh >> 4, hh = bh & 15;
#pragma unroll
  for (int r = 0; r < 16; r++) {
    int qr = (r & 3) + ((r >> 2) << 3) + (hi << 2);
    float invqA = 1.0f / accLA[r];
    float invqB = 1.0f / accLB[r];
    size_t baseA = ((size_t)(bb * Tt + qgA + qr)) * Dd + (hh << 6) + l31;
    size_t baseB = ((size_t)(bb * Tt + qgB + qr)) * Dd + (hh << 6) + l31;
    yb[baseA] = f2b(accA0[r] * invqA);
    yb[baseA + 32] = f2b(accA1[r] * invqA);
    yb[baseB] = f2b(accB0[r] * invqB);
    yb[baseB + 32] = f2b(accB1[r] * invqB);
  }
}

extern "C" void kernel_launch(void* const* d_in, const int* in_sizes, int n_in,
                              void* d_out, int out_size, void* d_ws, size_t ws_size,
                              hipStream_t stream) {
  const float* x = (const float*)d_in[0];
  const float* Wk = (const float*)d_in[1];
  const float* bk = (const float*)d_in[2];
  const float* Wq = (const float*)d_in[3];
  const float* bq = (const float*)d_in[4];
  const float* Wv = (const float*)d_in[5];
  const float* bv = (const float*)d_in[6];
  const float* Wp = (const float*)d_in[7];
  const float* bp = (const float*)d_in[8];
  float* out = (float*)d_out;

  char* ws = (char*)d_ws;
  unsigned short* xb  = (unsigned short*)(ws);                       // 16MB
  unsigned short* WkT = (unsigned short*)(ws + (16ull << 20));       // 2MB each
  unsigned short* WqT = (unsigned short*)(ws + (18ull << 20));
  unsigned short* WvT = (unsigned short*)(ws + (20ull << 20));
  unsigned short* WpT = (unsigned short*)(ws + (22ull << 20));
  unsigned short* Qb  = (unsigned short*)(ws + (24ull << 20));       // 16MB
  unsigned short* Kb  = (unsigned short*)(ws + (40ull << 20));       // 16MB
  unsigned short* VTb = (unsigned short*)(ws + (56ull << 20));       // 16MB
  unsigned short* yb  = (unsigned short*)(ws + (72ull << 20));       // 16MB (ends 88MB)

  k_convert_x<<<4096, 256, 0, stream>>>(x, xb);
  k_transpose_w<<<dim3(1024, 4), 256, 0, stream>>>(Wk, Wq, Wv, Wp, WkT, WqT, WvT, WpT);
  k_gemm3<<<dim3(64, 8), 256, 0, stream>>>(xb, WqT, WkT, WvT, bq, bk, bv,
                                           Qb, Kb, VTb);
  k_attn<<<512, 256, 0, stream>>>(Qb, Kb, VTb, yb);
  k_gemm<<<dim3(64, 8), 256, 0, stream>>>(yb, WpT, bp, out);
}

// Round 23
// 152.993 us; speedup vs baseline: 1.0507x; 1.0039x over previous
//
#include <hip/hip_runtime.h>
#include <stdint.h>

#define Bb 4
#define Tt 2048
#define Dd 1024
#define Hh 16
#define HDd 64
#define Mm 8192   // Bb*Tt

typedef __attribute__((ext_vector_type(8))) short bf16x8;
typedef __attribute__((ext_vector_type(4))) float f32x4;
typedef __attribute__((ext_vector_type(16))) float f32x16;

#define MFMA(a, b, c) __builtin_amdgcn_mfma_f32_16x16x32_bf16(a, b, c, 0, 0, 0)
#define MFMA32(a, b, c) __builtin_amdgcn_mfma_f32_32x32x16_bf16(a, b, c, 0, 0, 0)

#define LOG2E 1.44269504088896340736f
#if __has_builtin(__builtin_amdgcn_exp2f)
#define EXP2(x) __builtin_amdgcn_exp2f(x)
#else
#define EXP2(x) __expf((x) * 0.69314718055994530942f)
#endif

union vfu { uint2 u2[2]; bf16x8 v; };
union apu { uint32_t u[4]; bf16x8 v; };

__device__ __forceinline__ unsigned short f2b(float f) {
  union { float f; uint32_t u; } v; v.f = f;
  return (unsigned short)((v.u + 0x7FFFu + ((v.u >> 16) & 1u)) >> 16);
}

// pack two f32 -> bf16x2 (compiler emits v_cvt_pk_bf16_f32)
__device__ __forceinline__ uint32_t pk2(float a, float b) {
  union { __bf16 h[2]; uint32_t u; } x;
  x.h[0] = (__bf16)a; x.h[1] = (__bf16)b;
  return x.u;
}

__device__ __forceinline__ void gload_lds16(const void* g, void* l) {
  __builtin_amdgcn_global_load_lds(
      (const __attribute__((address_space(1))) void*)g,
      (__attribute__((address_space(3))) void*)l, 16, 0, 0);
}

// ---------------- x f32 -> bf16 ----------------
__global__ __launch_bounds__(256) void k_convert_x(const float* __restrict__ x,
                                                   unsigned short* __restrict__ xb) {
  int i = (blockIdx.x * 256 + threadIdx.x) * 8;
  float4 a = *(const float4*)(x + i);
  float4 b = *(const float4*)(x + i + 4);
  uint4 o;
  o.x = f2b(a.x) | ((uint32_t)f2b(a.y) << 16);
  o.y = f2b(a.z) | ((uint32_t)f2b(a.w) << 16);
  o.z = f2b(b.x) | ((uint32_t)f2b(b.y) << 16);
  o.w = f2b(b.z) | ((uint32_t)f2b(b.w) << 16);
  *(uint4*)(xb + i) = o;
}

// ---------------- W [K][N] f32 -> Wt [N][K] bf16 ----------------
__global__ __launch_bounds__(256) void k_transpose_w(
    const float* __restrict__ Wk, const float* __restrict__ Wq,
    const float* __restrict__ Wv, const float* __restrict__ Wp,
    unsigned short* __restrict__ WkT, unsigned short* __restrict__ WqT,
    unsigned short* __restrict__ WvT, unsigned short* __restrict__ WpT) {
  const float* W; unsigned short* O;
  int wsel = blockIdx.y;
  W = wsel == 0 ? Wk : wsel == 1 ? Wq : wsel == 2 ? Wv : Wp;
  O = wsel == 0 ? WkT : wsel == 1 ? WqT : wsel == 2 ? WvT : WpT;
  __shared__ unsigned short tile[32][36];
  int kb = (blockIdx.x >> 5) << 5;
  int nb = (blockIdx.x & 31) << 5;
  int t = threadIdx.x;
  int r = t >> 3, c4 = (t & 7) << 2;
  float4 v = *(const float4*)(W + (size_t)(kb + r) * Dd + nb + c4);
  tile[r][c4 + 0] = f2b(v.x); tile[r][c4 + 1] = f2b(v.y);
  tile[r][c4 + 2] = f2b(v.z); tile[r][c4 + 3] = f2b(v.w);
  __syncthreads();
  uint2 o;
  o.x = tile[c4 + 0][r] | ((uint32_t)tile[c4 + 1][r] << 16);
  o.y = tile[c4 + 2][r] | ((uint32_t)tile[c4 + 3][r] << 16);
  *(uint2*)(O + (size_t)(nb + r) * Dd + kb + c4) = o;
}

// ---------------- fused QKV GEMM: xb @ {Wq,Wk,Wv}^T + bias ----------------
// Double-buffered staging (neutral vs serial, kept). LDS 64 KB.
__global__ __launch_bounds__(256, 2) void k_gemm3(
    const unsigned short* __restrict__ A,
    const unsigned short* __restrict__ BtQ, const unsigned short* __restrict__ BtK,
    const unsigned short* __restrict__ BtV,
    const float* __restrict__ bq, const float* __restrict__ bk,
    const float* __restrict__ bv,
    unsigned short* __restrict__ Qb, unsigned short* __restrict__ Kb,
    unsigned short* __restrict__ VTb) {
  __shared__ __align__(16) unsigned short Al[2][128 * 32];
  __shared__ __align__(16) unsigned short Bl[2][3][128 * 32];
  int tid = threadIdx.x;
  int lane = tid & 63, wid = tid >> 6;
  int wr = wid >> 1, wc = wid & 1;
  int lq = lane & 15, lh = lane >> 4;
  int mb = blockIdx.x * 128;
  int nb = blockIdx.y << 7;

  int srow = (wid << 5) + (lane >> 2);
  int scol = (lane & 3) << 3;
  const unsigned short* Ag = A + (size_t)(mb + srow) * Dd + scol;
  const unsigned short* Bg0 = BtQ + (size_t)(nb + srow) * Dd + scol;
  const unsigned short* Bg1 = BtK + (size_t)(nb + srow) * Dd + scol;
  const unsigned short* Bg2 = BtV + (size_t)(nb + srow) * Dd + scol;
  int lofs = wid << 10;   // wave-uniform LDS offset (wid*32 rows * 32 elems)

#define STAGE3(kb_, bi_) do {                                            \
    gload_lds16(Ag + (kb_), &Al[bi_][0] + lofs);                         \
    gload_lds16(Ag + (kb_) + 16 * Dd, &Al[bi_][0] + lofs + 16 * 32);     \
    gload_lds16(Bg0 + (kb_), &Bl[bi_][0][0] + lofs);                     \
    gload_lds16(Bg0 + (kb_) + 16 * Dd, &Bl[bi_][0][0] + lofs + 16 * 32); \
    gload_lds16(Bg1 + (kb_), &Bl[bi_][1][0] + lofs);                     \
    gload_lds16(Bg1 + (kb_) + 16 * Dd, &Bl[bi_][1][0] + lofs + 16 * 32); \
    gload_lds16(Bg2 + (kb_), &Bl[bi_][2][0] + lofs);                     \
    gload_lds16(Bg2 + (kb_) + 16 * Dd, &Bl[bi_][2][0] + lofs + 16 * 32); \
  } while (0)

  f32x4 zero = {0.f, 0.f, 0.f, 0.f};
  f32x4 acc[3][4][4];
#pragma unroll
  for (int s = 0; s < 3; s++)
#pragma unroll
    for (int m = 0; m < 4; m++)
#pragma unroll
      for (int n = 0; n < 4; n++) acc[s][m][n] = zero;

  STAGE3(0, 0);
  __syncthreads();

  int cur = 0;
  for (int kb = 0; kb < Dd; kb += 32) {
    if (kb + 32 < Dd) STAGE3(kb + 32, cur ^ 1);   // hides under compute(kb)
    bf16x8 af[4];
#pragma unroll
    for (int m = 0; m < 4; m++)
      af[m] = *(const bf16x8*)(&Al[cur][0] +
                               (((wr << 6) + (m << 4) + lq) << 5) + (lh << 3));
#pragma unroll
    for (int s = 0; s < 3; s++) {
      bf16x8 bf[4];
#pragma unroll
      for (int n = 0; n < 4; n++)
        bf[n] = *(const bf16x8*)(&Bl[cur][s][0] +
                                 (((wc << 6) + (n << 4) + lq) << 5) + (lh << 3));
      __builtin_amdgcn_s_setprio(1);
#pragma unroll
      for (int m = 0; m < 4; m++)
#pragma unroll
        for (int n = 0; n < 4; n++) acc[s][m][n] = MFMA(af[m], bf[n], acc[s][m][n]);
      __builtin_amdgcn_s_setprio(0);
    }
    __syncthreads();   // drains this iter's staging; joins readers of cur
    cur ^= 1;
  }
#undef STAGE3

  int b_idx = mb >> 11;
#pragma unroll
  for (int s = 0; s < 3; s++) {
#pragma unroll
    for (int n = 0; n < 4; n++) {
      int col = nb + (wc << 6) + (n << 4) + lq;
      float bbias = (s == 0) ? bq[col] : (s == 1) ? bk[col] : bv[col];
      int hh = col >> 6, hd = col & 63;
#pragma unroll
      for (int m = 0; m < 4; m++) {
        int row0 = mb + (wr << 6) + (m << 4) + (lh << 2);
        int t0 = row0 & 2047;
        if (s == 2) {          // V -> [B,H,64,T], t-swizzled
          float v0 = acc[s][m][n][0] + bbias, v1 = acc[s][m][n][1] + bbias;
          float v2 = acc[s][m][n][2] + bbias, v3 = acc[s][m][n][3] + bbias;
          uint2 pv;
          pv.x = f2b(v0) | ((uint32_t)f2b(v1) << 16);
          pv.y = f2b(v2) | ((uint32_t)f2b(v3) << 16);
          int t0s = t0 ^ ((hd & 7) << 3);
          *(uint2*)(VTb + ((size_t)(b_idx * 16 + hh) * 64 + hd) * Tt + t0s) = pv;
        } else {               // Q (scaled) / K (row-swizzled) -> [B,H,T,64]
          unsigned short* O = (s == 0) ? Qb : Kb;
          float sc = (s == 0) ? (0.125f * LOG2E) : 1.0f;
#pragma unroll
          for (int r = 0; r < 4; r++) {
            float v = (acc[s][m][n][r] + bbias) * sc;
            int trow = t0 + r;
            int hds = (s == 0) ? hd : (hd ^ ((trow & 7) << 3));
            O[((size_t)(b_idx * 16 + hh) * Tt + trow) * 64 + hds] = f2b(v);
          }
        }
      }
    }
  }
}

// ---------------- GEMM (projection): A[M][1024] bf16 @ Bt^T + bias -> f32 ----
__global__ __launch_bounds__(256) void k_gemm(
    const unsigned short* __restrict__ A,
    const unsigned short* __restrict__ Bt0,
    const float* __restrict__ bias0,
    float* __restrict__ Pout) {
  __shared__ __align__(16) unsigned short Al[2][128 * 32];
  __shared__ __align__(16) unsigned short Bl[2][128 * 32];
  int tid = threadIdx.x;
  int lane = tid & 63, wid = tid >> 6;
  int wr = wid >> 1, wc = wid & 1;
  int lq = lane & 15, lh = lane >> 4;
  int mb = blockIdx.x * 128;
  int nb = blockIdx.y << 7;

  int srow = (wid << 5) + (lane >> 2);
  int scol = (lane & 3) << 3;
  const unsigned short* Ag = A + (size_t)(mb + srow) * Dd + scol;
  const unsigned short* Bg = Bt0 + (size_t)(nb + srow) * Dd + scol;
  int lofs = wid << 10;

#define STAGEP(kb_, bi_) do {                                            \
    gload_lds16(Ag + (kb_), &Al[bi_][0] + lofs);                         \
    gload_lds16(Ag + (kb_) + 16 * Dd, &Al[bi_][0] + lofs + 16 * 32);     \
    gload_lds16(Bg + (kb_), &Bl[bi_][0] + lofs);                         \
    gload_lds16(Bg + (kb_) + 16 * Dd, &Bl[bi_][0] + lofs + 16 * 32);     \
  } while (0)

  f32x4 zero = {0.f, 0.f, 0.f, 0.f};
  f32x4 acc[4][4];
#pragma unroll
  for (int m = 0; m < 4; m++)
#pragma unroll
    for (int n = 0; n < 4; n++) acc[m][n] = zero;

  STAGEP(0, 0);
  __syncthreads();

  int cur = 0;
  for (int kb = 0; kb < Dd; kb += 32) {
    if (kb + 32 < Dd) STAGEP(kb + 32, cur ^ 1);
    bf16x8 af[4], bf[4];
#pragma unroll
    for (int m = 0; m < 4; m++)
      af[m] = *(const bf16x8*)(&Al[cur][0] +
                               (((wr << 6) + (m << 4) + lq) << 5) + (lh << 3));
#pragma unroll
    for (int n = 0; n < 4; n++)
      bf[n] = *(const bf16x8*)(&Bl[cur][0] +
                               (((wc << 6) + (n << 4) + lq) << 5) + (lh << 3));
    __builtin_amdgcn_s_setprio(1);
#pragma unroll
    for (int m = 0; m < 4; m++)
#pragma unroll
      for (int n = 0; n < 4; n++) acc[m][n] = MFMA(af[m], bf[n], acc[m][n]);
    __builtin_amdgcn_s_setprio(0);
    __syncthreads();
    cur ^= 1;
  }
#undef STAGEP

#pragma unroll
  for (int n = 0; n < 4; n++) {
    int col = nb + (wc << 6) + (n << 4) + lq;
    float bb = bias0[col];
#pragma unroll
    for (int m = 0; m < 4; m++) {
      int row0 = mb + (wr << 6) + (m << 4) + (lh << 2);
#pragma unroll
      for (int r = 0; r < 4; r++)
        Pout[(size_t)(row0 + r) * Dd + col] = acc[m][n][r] + bb;
    }
  }
}

// ---------------- flash attention (causal), Q pre-scaled by 0.125*log2e ----------
// UNIFORM-WORK pairing at the wave level: each wave owns 32 q-rows of a HEAVY
// 128-row q-tile (15-p) [B-half] and 32 q-rows of the complementary LIGHT tile
// (p) [A-half], sharing all staged K/V. Per-block compute = (p+1)*2 +
// (15-2p)*1 = 17 half-tile units, exactly uniform across all 512 blocks ->
// no triangular drain; every SIMD active to block end via its heavy half.
__global__ __launch_bounds__(256, 2) void k_attn(
    const unsigned short* __restrict__ Qb, const unsigned short* __restrict__ Kb,
    const unsigned short* __restrict__ VTb, unsigned short* __restrict__ yb) {
  __shared__ __align__(16) unsigned short KL[2][8192];  // 128 kv rows x 64 hd
  __shared__ __align__(16) unsigned short VL[2][8192];  // 64 hd rows x 128 t
  int b = blockIdx.x;
  int p = b >> 6;                            // 0..7 (heavy tile 15-p staged first)
  int rr6 = b & 63;
  int bh = ((rr6 & 7) << 3) | (rr6 >> 3);    // XCD x holds heads 8x..8x+7
  int tid = threadIdx.x, lane = tid & 63, w = tid >> 6;
  int l31 = lane & 31, hi = lane >> 5;
  const unsigned short* __restrict__ Qh = Qb + (size_t)bh * Tt * 64;
  const unsigned short* __restrict__ Kh = Kb + (size_t)bh * Tt * 64;
  const unsigned short* __restrict__ Vh = VTb + (size_t)bh * 64 * Tt;
  int qgA = (p << 7) + (w << 5);             // LIGHT half: tile p
  int qgB = ((15 - p) << 7) + (w << 5);      // HEAVY half: tile 15-p

  bf16x8 qfA[4], qfB[4];
#pragma unroll
  for (int c = 0; c < 4; c++) {
    qfA[c] = *(const bf16x8*)(Qh + (size_t)(qgA + l31) * 64 + (c << 4) + (hi << 3));
    qfB[c] = *(const bf16x8*)(Qh + (size_t)(qgB + l31) * 64 + (c << 4) + (hi << 3));
  }

  f32x16 accA0, accA1, accB0, accB1, accLA, accLB;
#pragma unroll
  for (int i = 0; i < 16; i++) {
    accA0[i] = 0.f; accA1[i] = 0.f; accB0[i] = 0.f; accB1[i] = 0.f;
    accLA[i] = 0.f; accLB[i] = 0.f;
  }
  apu onesf;
  onesf.u[0] = onesf.u[1] = onesf.u[2] = onesf.u[3] = 0x3F803F80u;  // bf16 1.0 x8

  int jmaxb = 15 - p;          // kv tiles (128 rows) needed by the heavy tile
  int srowK = lane >> 3, scolK = (lane & 7) << 3;
  int rowbK = w << 5;          // wave stages 32 K rows per tile
  int srowV = lane >> 4, scolV = (lane & 15) << 3;
  int rowbV = w << 4;          // wave stages 16 V rows (x128 t) per tile
  int swz = l31 & 7;

#define STAGE(kvt_, bi_) do {                                                        \
    int kv_ = (kvt_) << 7;                                                           \
    gload_lds16(Kh + (size_t)(kv_ + rowbK + srowK) * 64 + scolK,                     \
                &KL[bi_][rowbK << 6]);                                               \
    gload_lds16(Kh + (size_t)(kv_ + rowbK + 8 + srowK) * 64 + scolK,                 \
                &KL[bi_][(rowbK + 8) << 6]);                                         \
    gload_lds16(Kh + (size_t)(kv_ + rowbK + 16 + srowK) * 64 + scolK,                \
                &KL[bi_][(rowbK + 16) << 6]);                                        \
    gload_lds16(Kh + (size_t)(kv_ + rowbK + 24 + srowK) * 64 + scolK,                \
                &KL[bi_][(rowbK + 24) << 6]);                                        \
    gload_lds16(Vh + (size_t)(rowbV + srowV) * Tt + kv_ + scolV,                     \
                &VL[bi_][rowbV << 7]);                                               \
    gload_lds16(Vh + (size_t)(rowbV + 4 + srowV) * Tt + kv_ + scolV,                 \
                &VL[bi_][(rowbV + 4) << 7]);                                         \
    gload_lds16(Vh + (size_t)(rowbV + 8 + srowV) * Tt + kv_ + scolV,                 \
                &VL[bi_][(rowbV + 8) << 7]);                                         \
    gload_lds16(Vh + (size_t)(rowbV + 12 + srowV) * Tt + kv_ + scolV,                \
                &VL[bi_][(rowbV + 12) << 7]);                                        \
  } while (0)

  STAGE(0, 0);
  __syncthreads();

  int cur = 0;
  for (int jt = 0; jt <= jmaxb; ++jt) {
    if (jt < jmaxb) STAGE(jt + 1, cur ^ 1);  // latency hides under compute
    int base_kv = jt << 7;
    const unsigned short* KB = &KL[cur][0];
    const unsigned short* VB = &VL[cur][0];
#pragma unroll
    for (int n2 = 0; n2 < 4; n2++) {
      int relB = qgB - base_kv - (n2 << 5);   // heavy half, wave-uniform, mult 32
      int relA = qgA - base_kv - (n2 << 5);   // light half
      if (relB >= 0) {                        // heavy has unmasked rows
        bool doA = (relA >= 0);               // light not fully masked
        bf16x8 kf[4];
        int krowb = ((n2 << 5) + l31) << 6;
#pragma unroll
        for (int c = 0; c < 4; c++)
          kf[c] = *(const bf16x8*)(KB + krowb + ((((c << 1) + hi) ^ swz) << 3));
        f32x16 sA, sB;
#pragma unroll
        for (int i = 0; i < 16; i++) { sA[i] = 0.f; sB[i] = 0.f; }
        __builtin_amdgcn_s_setprio(1);
        if (doA) {
#pragma unroll
          for (int c = 0; c < 4; c++) {
            sA = MFMA32(kf[c], qfA[c], sA);
            sB = MFMA32(kf[c], qfB[c], sB);
          }
        } else {
#pragma unroll
          for (int c = 0; c < 4; c++) sB = MFMA32(kf[c], qfB[c], sB);
        }
        __builtin_amdgcn_s_setprio(0);
        float pA[16], pB[16];
        if (relB == 0) {       // heavy diagonal sub-block
          int rB = l31;        // relB + l31
#pragma unroll
          for (int r = 0; r < 16; r++) {
            int krow = (r & 3) + ((r >> 2) << 3) + (hi << 2);
            pB[r] = EXP2(krow > rB ? -1e30f : sB[r]);
          }
        } else {
#pragma unroll
          for (int r = 0; r < 16; r++) pB[r] = EXP2(sB[r]);
        }
        if (doA) {
          if (relA == 0) {     // light diagonal sub-block
            int rA = l31;
#pragma unroll
            for (int r = 0; r < 16; r++) {
              int krow = (r & 3) + ((r >> 2) << 3) + (hi << 2);
              pA[r] = EXP2(krow > rA ? -1e30f : sA[r]);
            }
          } else {
#pragma unroll
            for (int r = 0; r < 16; r++) pA[r] = EXP2(sA[r]);
          }
        }
        vfu vf[2][2];
#pragma unroll
        for (int n2v = 0; n2v < 2; n2v++) {
          int vrowb = ((n2v << 5) + l31) << 7;   // V row stride = 128 t
#pragma unroll
          for (int cc = 0; cc < 2; cc++) {
            int blk0 = (n2 << 2) + (cc << 1);    // t-block in [0,15]
            vf[n2v][cc].u2[0] =
                *(const uint2*)(VB + vrowb + ((blk0 ^ swz) << 3) + (hi << 2));
            vf[n2v][cc].u2[1] =
                *(const uint2*)(VB + vrowb + (((blk0 + 1) ^ swz) << 3) + (hi << 2));
          }
        }
        apu b0, b1;
#pragma unroll
        for (int g = 0; g < 4; g++) {
          b0.u[g] = pk2(pB[2 * g], pB[2 * g + 1]);
          b1.u[g] = pk2(pB[8 + 2 * g], pB[8 + 2 * g + 1]);
        }
        __builtin_amdgcn_s_setprio(1);
        accB0 = MFMA32(b0.v, vf[0][0].v, accB0);
        accB1 = MFMA32(b0.v, vf[1][0].v, accB1);
        accLB = MFMA32(b0.v, onesf.v, accLB);
        accB0 = MFMA32(b1.v, vf[0][1].v, accB0);
        accB1 = MFMA32(b1.v, vf[1][1].v, accB1);
        accLB = MFMA32(b1.v, onesf.v, accLB);
        __builtin_amdgcn_s_setprio(0);
        if (doA) {
          apu a0, a1;
#pragma unroll
          for (int g = 0; g < 4; g++) {
            a0.u[g] = pk2(pA[2 * g], pA[2 * g + 1]);
            a1.u[g] = pk2(pA[8 + 2 * g], pA[8 + 2 * g + 1]);
          }
          __builtin_amdgcn_s_setprio(1);
          accA0 = MFMA32(a0.v, vf[0][0].v, accA0);
          accA1 = MFMA32(a0.v, vf[1][0].v, accA1);
          accLA = MFMA32(a0.v, onesf.v, accLA);
          accA0 = MFMA32(a1.v, vf[0][1].v, accA0);
          accA1 = MFMA32(a1.v, vf[1][1].v, accA1);
          accLA = MFMA32(a1.v, onesf.v, accLA);
          __builtin_amdgcn_s_setprio(0);
        }
      }
    }
    __syncthreads();
    cur ^= 1;
  }
#undef STAGE

  // accL[r] = lsum for q = crow(r,hi) -- same indexing as accA/accB rows.
  int bb = bh >> 4, hh = bh & 15;
#pragma unroll
  for (int r = 0; r < 16; r++) {
    int qr = (r & 3) + ((r >> 2) << 3) + (hi << 2);
    float invqA = 1.0f / accLA[r];
    float invqB = 1.0f / accLB[r];
    size_t baseA = ((size_t)(bb * Tt + qgA + qr)) * Dd + (hh << 6) + l31;
    size_t baseB = ((size_t)(bb * Tt + qgB + qr)) * Dd + (hh << 6) + l31;
    yb[baseA] = f2b(accA0[r] * invqA);
    yb[baseA + 32] = f2b(accA1[r] * invqA);
    yb[baseB] = f2b(accB0[r] * invqB);
    yb[baseB + 32] = f2b(accB1[r] * invqB);
  }
}

extern "C" void kernel_launch(void* const* d_in, const int* in_sizes, int n_in,
                              void* d_out, int out_size, void* d_ws, size_t ws_size,
                              hipStream_t stream) {
  const float* x = (const float*)d_in[0];
  const float* Wk = (const float*)d_in[1];
  const float* bk = (const float*)d_in[2];
  const float* Wq = (const float*)d_in[3];
  const float* bq = (const float*)d_in[4];
  const float* Wv = (const float*)d_in[5];
  const float* bv = (const float*)d_in[6];
  const float* Wp = (const float*)d_in[7];
  const float* bp = (const float*)d_in[8];
  float* out = (float*)d_out;

  char* ws = (char*)d_ws;
  unsigned short* xb  = (unsigned short*)(ws);                       // 16MB
  unsigned short* WkT = (unsigned short*)(ws + (16ull << 20));       // 2MB each
  unsigned short* WqT = (unsigned short*)(ws + (18ull << 20));
  unsigned short* WvT = (unsigned short*)(ws + (20ull << 20));
  unsigned short* WpT = (unsigned short*)(ws + (22ull << 20));
  unsigned short* Qb  = (unsigned short*)(ws + (24ull << 20));       // 16MB
  unsigned short* Kb  = (unsigned short*)(ws + (40ull << 20));       // 16MB
  unsigned short* VTb = (unsigned short*)(ws + (56ull << 20));       // 16MB
  unsigned short* yb  = (unsigned short*)(ws + (72ull << 20));       // 16MB (ends 88MB)

  k_convert_x<<<4096, 256, 0, stream>>>(x, xb);
  k_transpose_w<<<dim3(1024, 4), 256, 0, stream>>>(Wk, Wq, Wv, Wp, WkT, WqT, WvT, WpT);
  k_gemm3<<<dim3(64, 8), 256, 0, stream>>>(xb, WqT, WkT, WvT, bq, bk, bv,
                                           Qb, Kb, VTb);
  k_attn<<<512, 256, 0, stream>>>(Qb, Kb, VTb, yb);
  k_gemm<<<dim3(64, 8), 256, 0, stream>>>(yb, WpT, bp, out);
}

// Round 24
// 151.618 us; speedup vs baseline: 1.0602x; 1.0091x over previous
//
#include <hip/hip_runtime.h>
#include <stdint.h>

#define Bb 4
#define Tt 2048
#define Dd 1024
#define Hh 16
#define HDd 64
#define Mm 8192   // Bb*Tt

typedef __attribute__((ext_vector_type(8))) short bf16x8;
typedef __attribute__((ext_vector_type(4))) float f32x4;
typedef __attribute__((ext_vector_type(16))) float f32x16;

#define MFMA(a, b, c) __builtin_amdgcn_mfma_f32_16x16x32_bf16(a, b, c, 0, 0, 0)
#define MFMA32(a, b, c) __builtin_amdgcn_mfma_f32_32x32x16_bf16(a, b, c, 0, 0, 0)

#define LOG2E 1.44269504088896340736f
#if __has_builtin(__builtin_amdgcn_exp2f)
#define EXP2(x) __builtin_amdgcn_exp2f(x)
#else
#define EXP2(x) __expf((x) * 0.69314718055994530942f)
#endif

union vfu { uint2 u2[2]; bf16x8 v; };
union apu { uint32_t u[4]; bf16x8 v; };

__device__ __forceinline__ unsigned short f2b(float f) {
  union { float f; uint32_t u; } v; v.f = f;
  return (unsigned short)((v.u + 0x7FFFu + ((v.u >> 16) & 1u)) >> 16);
}

// pack two f32 -> bf16x2 (compiler emits v_cvt_pk_bf16_f32)
__device__ __forceinline__ uint32_t pk2(float a, float b) {
  union { __bf16 h[2]; uint32_t u; } x;
  x.h[0] = (__bf16)a; x.h[1] = (__bf16)b;
  return x.u;
}

__device__ __forceinline__ void gload_lds16(const void* g, void* l) {
  __builtin_amdgcn_global_load_lds(
      (const __attribute__((address_space(1))) void*)g,
      (__attribute__((address_space(3))) void*)l, 16, 0, 0);
}

// ---------------- merged front-end: x convert (blocks 0..4095) + W transpose ----
__global__ __launch_bounds__(256) void k_front(
    const float* __restrict__ x, unsigned short* __restrict__ xb,
    const float* __restrict__ Wk, const float* __restrict__ Wq,
    const float* __restrict__ Wv, const float* __restrict__ Wp,
    unsigned short* __restrict__ WkT, unsigned short* __restrict__ WqT,
    unsigned short* __restrict__ WvT, unsigned short* __restrict__ WpT) {
  __shared__ unsigned short tile[32][36];
  int b = blockIdx.x;
  if (b < 4096) {
    int i = (b * 256 + threadIdx.x) * 8;
    float4 a = *(const float4*)(x + i);
    float4 c = *(const float4*)(x + i + 4);
    uint4 o;
    o.x = f2b(a.x) | ((uint32_t)f2b(a.y) << 16);
    o.y = f2b(a.z) | ((uint32_t)f2b(a.w) << 16);
    o.z = f2b(c.x) | ((uint32_t)f2b(c.y) << 16);
    o.w = f2b(c.z) | ((uint32_t)f2b(c.w) << 16);
    *(uint4*)(xb + i) = o;
  } else {
    int bb = b - 4096;
    int wsel = bb >> 10;
    int bx = bb & 1023;
    const float* W; unsigned short* O;
    W = wsel == 0 ? Wk : wsel == 1 ? Wq : wsel == 2 ? Wv : Wp;
    O = wsel == 0 ? WkT : wsel == 1 ? WqT : wsel == 2 ? WvT : WpT;
    int kb = (bx >> 5) << 5;
    int nb = (bx & 31) << 5;
    int t = threadIdx.x;
    int r = t >> 3, c4 = (t & 7) << 2;
    float4 v = *(const float4*)(W + (size_t)(kb + r) * Dd + nb + c4);
    tile[r][c4 + 0] = f2b(v.x); tile[r][c4 + 1] = f2b(v.y);
    tile[r][c4 + 2] = f2b(v.z); tile[r][c4 + 3] = f2b(v.w);
    __syncthreads();
    uint2 o;
    o.x = tile[c4 + 0][r] | ((uint32_t)tile[c4 + 1][r] << 16);
    o.y = tile[c4 + 2][r] | ((uint32_t)tile[c4 + 3][r] << 16);
    *(uint2*)(O + (size_t)(nb + r) * Dd + kb + c4) = o;
  }
}

// ---------------- fused QKV GEMM: xb @ {Wq,Wk,Wv}^T + bias ----------------
// Double-buffered staging + LDS XOR-swizzle (rule 21): linear LDS dest,
// pre-swizzled per-lane global source (col-slot ^= row&3), swizzled reads
// (lh ^ (lq&3)) -> fragment-read bank conflicts 8-way -> 4-way.
__global__ __launch_bounds__(256, 2) void k_gemm3(
    const unsigned short* __restrict__ A,
    const unsigned short* __restrict__ BtQ, const unsigned short* __restrict__ BtK,
    const unsigned short* __restrict__ BtV,
    const float* __restrict__ bq, const float* __restrict__ bk,
    const float* __restrict__ bv,
    unsigned short* __restrict__ Qb, unsigned short* __restrict__ Kb,
    unsigned short* __restrict__ VTb) {
  __shared__ __align__(16) unsigned short Al[2][128 * 32];
  __shared__ __align__(16) unsigned short Bl[2][3][128 * 32];
  int tid = threadIdx.x;
  int lane = tid & 63, wid = tid >> 6;
  int wr = wid >> 1, wc = wid & 1;
  int lq = lane & 15, lh = lane >> 4;
  int mb = blockIdx.x * 128;
  int nb = blockIdx.y << 7;

  int srow = (wid << 5) + (lane >> 2);
  int scol = (((lane & 3) ^ ((lane >> 2) & 3)) << 3);  // pre-swizzled source slot
  const unsigned short* Ag = A + (size_t)(mb + srow) * Dd + scol;
  const unsigned short* Bg0 = BtQ + (size_t)(nb + srow) * Dd + scol;
  const unsigned short* Bg1 = BtK + (size_t)(nb + srow) * Dd + scol;
  const unsigned short* Bg2 = BtV + (size_t)(nb + srow) * Dd + scol;
  int lofs = wid << 10;   // wave-uniform LDS offset (wid*32 rows * 32 elems)
  int rsw = (lh ^ (lq & 3)) << 3;   // swizzled read slot (row&3 == lq&3)

#define STAGE3(kb_, bi_) do {                                            \
    gload_lds16(Ag + (kb_), &Al[bi_][0] + lofs);                         \
    gload_lds16(Ag + (kb_) + 16 * Dd, &Al[bi_][0] + lofs + 16 * 32);     \
    gload_lds16(Bg0 + (kb_), &Bl[bi_][0][0] + lofs);                     \
    gload_lds16(Bg0 + (kb_) + 16 * Dd, &Bl[bi_][0][0] + lofs + 16 * 32); \
    gload_lds16(Bg1 + (kb_), &Bl[bi_][1][0] + lofs);                     \
    gload_lds16(Bg1 + (kb_) + 16 * Dd, &Bl[bi_][1][0] + lofs + 16 * 32); \
    gload_lds16(Bg2 + (kb_), &Bl[bi_][2][0] + lofs);                     \
    gload_lds16(Bg2 + (kb_) + 16 * Dd, &Bl[bi_][2][0] + lofs + 16 * 32); \
  } while (0)

  f32x4 zero = {0.f, 0.f, 0.f, 0.f};
  f32x4 acc[3][4][4];
#pragma unroll
  for (int s = 0; s < 3; s++)
#pragma unroll
    for (int m = 0; m < 4; m++)
#pragma unroll
      for (int n = 0; n < 4; n++) acc[s][m][n] = zero;

  STAGE3(0, 0);
  __syncthreads();

  int cur = 0;
  for (int kb = 0; kb < Dd; kb += 32) {
    if (kb + 32 < Dd) STAGE3(kb + 32, cur ^ 1);   // hides under compute(kb)
    bf16x8 af[4];
#pragma unroll
    for (int m = 0; m < 4; m++)
      af[m] = *(const bf16x8*)(&Al[cur][0] +
                               (((wr << 6) + (m << 4) + lq) << 5) + rsw);
#pragma unroll
    for (int s = 0; s < 3; s++) {
      bf16x8 bf[4];
#pragma unroll
      for (int n = 0; n < 4; n++)
        bf[n] = *(const bf16x8*)(&Bl[cur][s][0] +
                                 (((wc << 6) + (n << 4) + lq) << 5) + rsw);
      __builtin_amdgcn_s_setprio(1);
#pragma unroll
      for (int m = 0; m < 4; m++)
#pragma unroll
        for (int n = 0; n < 4; n++) acc[s][m][n] = MFMA(af[m], bf[n], acc[s][m][n]);
      __builtin_amdgcn_s_setprio(0);
    }
    __syncthreads();   // drains this iter's staging; joins readers of cur
    cur ^= 1;
  }
#undef STAGE3

  int b_idx = mb >> 11;
#pragma unroll
  for (int s = 0; s < 3; s++) {
#pragma unroll
    for (int n = 0; n < 4; n++) {
      int col = nb + (wc << 6) + (n << 4) + lq;
      float bbias = (s == 0) ? bq[col] : (s == 1) ? bk[col] : bv[col];
      int hh = col >> 6, hd = col & 63;
#pragma unroll
      for (int m = 0; m < 4; m++) {
        int row0 = mb + (wr << 6) + (m << 4) + (lh << 2);
        int t0 = row0 & 2047;
        if (s == 2) {          // V -> [B,H,64,T], t-swizzled
          float v0 = acc[s][m][n][0] + bbias, v1 = acc[s][m][n][1] + bbias;
          float v2 = acc[s][m][n][2] + bbias, v3 = acc[s][m][n][3] + bbias;
          uint2 pv;
          pv.x = f2b(v0) | ((uint32_t)f2b(v1) << 16);
          pv.y = f2b(v2) | ((uint32_t)f2b(v3) << 16);
          int t0s = t0 ^ ((hd & 7) << 3);
          *(uint2*)(VTb + ((size_t)(b_idx * 16 + hh) * 64 + hd) * Tt + t0s) = pv;
        } else {               // Q (scaled) / K (row-swizzled) -> [B,H,T,64]
          unsigned short* O = (s == 0) ? Qb : Kb;
          float sc = (s == 0) ? (0.125f * LOG2E) : 1.0f;
#pragma unroll
          for (int r = 0; r < 4; r++) {
            float v = (acc[s][m][n][r] + bbias) * sc;
            int trow = t0 + r;
            int hds = (s == 0) ? hd : (hd ^ ((trow & 7) << 3));
            O[((size_t)(b_idx * 16 + hh) * Tt + trow) * 64 + hds] = f2b(v);
          }
        }
      }
    }
  }
}

// ---------------- GEMM (projection): A[M][1024] bf16 @ Bt^T + bias -> f32 ----
// Double-buffered + same source/read LDS swizzle as gemm3.
__global__ __launch_bounds__(256) void k_gemm(
    const unsigned short* __restrict__ A,
    const unsigned short* __restrict__ Bt0,
    const float* __restrict__ bias0,
    float* __restrict__ Pout) {
  __shared__ __align__(16) unsigned short Al[2][128 * 32];
  __shared__ __align__(16) unsigned short Bl[2][128 * 32];
  int tid = threadIdx.x;
  int lane = tid & 63, wid = tid >> 6;
  int wr = wid >> 1, wc = wid & 1;
  int lq = lane & 15, lh = lane >> 4;
  int mb = blockIdx.x * 128;
  int nb = blockIdx.y << 7;

  int srow = (wid << 5) + (lane >> 2);
  int scol = (((lane & 3) ^ ((lane >> 2) & 3)) << 3);  // pre-swizzled source slot
  const unsigned short* Ag = A + (size_t)(mb + srow) * Dd + scol;
  const unsigned short* Bg = Bt0 + (size_t)(nb + srow) * Dd + scol;
  int lofs = wid << 10;
  int rsw = (lh ^ (lq & 3)) << 3;

#define STAGEP(kb_, bi_) do {                                            \
    gload_lds16(Ag + (kb_), &Al[bi_][0] + lofs);                         \
    gload_lds16(Ag + (kb_) + 16 * Dd, &Al[bi_][0] + lofs + 16 * 32);     \
    gload_lds16(Bg + (kb_), &Bl[bi_][0] + lofs);                         \
    gload_lds16(Bg + (kb_) + 16 * Dd, &Bl[bi_][0] + lofs + 16 * 32);     \
  } while (0)

  f32x4 zero = {0.f, 0.f, 0.f, 0.f};
  f32x4 acc[4][4];
#pragma unroll
  for (int m = 0; m < 4; m++)
#pragma unroll
    for (int n = 0; n < 4; n++) acc[m][n] = zero;

  STAGEP(0, 0);
  __syncthreads();

  int cur = 0;
  for (int kb = 0; kb < Dd; kb += 32) {
    if (kb + 32 < Dd) STAGEP(kb + 32, cur ^ 1);
    bf16x8 af[4], bf[4];
#pragma unroll
    for (int m = 0; m < 4; m++)
      af[m] = *(const bf16x8*)(&Al[cur][0] +
                               (((wr << 6) + (m << 4) + lq) << 5) + rsw);
#pragma unroll
    for (int n = 0; n < 4; n++)
      bf[n] = *(const bf16x8*)(&Bl[cur][0] +
                               (((wc << 6) + (n << 4) + lq) << 5) + rsw);
    __builtin_amdgcn_s_setprio(1);
#pragma unroll
    for (int m = 0; m < 4; m++)
#pragma unroll
      for (int n = 0; n < 4; n++) acc[m][n] = MFMA(af[m], bf[n], acc[m][n]);
    __builtin_amdgcn_s_setprio(0);
    __syncthreads();
    cur ^= 1;
  }
#undef STAGEP

#pragma unroll
  for (int n = 0; n < 4; n++) {
    int col = nb + (wc << 6) + (n << 4) + lq;
    float bb = bias0[col];
#pragma unroll
    for (int m = 0; m < 4; m++) {
      int row0 = mb + (wr << 6) + (m << 4) + (lh << 2);
#pragma unroll
      for (int r = 0; r < 4; r++)
        Pout[(size_t)(row0 + r) * Dd + col] = acc[m][n][r] + bb;
    }
  }
}

// ---------------- flash attention (causal), Q pre-scaled by 0.125*log2e ----------
// r23 kernel unchanged (64.5us): heavy/light uniform wave pairing, 128-row KV
// tiles, dbuf staging, lsum via ones-MFMA.
__global__ __launch_bounds__(256, 2) void k_attn(
    const unsigned short* __restrict__ Qb, const unsigned short* __restrict__ Kb,
    const unsigned short* __restrict__ VTb, unsigned short* __restrict__ yb) {
  __shared__ __align__(16) unsigned short KL[2][8192];  // 128 kv rows x 64 hd
  __shared__ __align__(16) unsigned short VL[2][8192];  // 64 hd rows x 128 t
  int b = blockIdx.x;
  int p = b >> 6;                            // 0..7 (heavy tile 15-p)
  int rr6 = b & 63;
  int bh = ((rr6 & 7) << 3) | (rr6 >> 3);    // XCD x holds heads 8x..8x+7
  int tid = threadIdx.x, lane = tid & 63, w = tid >> 6;
  int l31 = lane & 31, hi = lane >> 5;
  const unsigned short* __restrict__ Qh = Qb + (size_t)bh * Tt * 64;
  const unsigned short* __restrict__ Kh = Kb + (size_t)bh * Tt * 64;
  const unsigned short* __restrict__ Vh = VTb + (size_t)bh * 64 * Tt;
  int qgA = (p << 7) + (w << 5);             // LIGHT half: tile p
  int qgB = ((15 - p) << 7) + (w << 5);      // HEAVY half: tile 15-p

  bf16x8 qfA[4], qfB[4];
#pragma unroll
  for (int c = 0; c < 4; c++) {
    qfA[c] = *(const bf16x8*)(Qh + (size_t)(qgA + l31) * 64 + (c << 4) + (hi << 3));
    qfB[c] = *(const bf16x8*)(Qh + (size_t)(qgB + l31) * 64 + (c << 4) + (hi << 3));
  }

  f32x16 accA0, accA1, accB0, accB1, accLA, accLB;
#pragma unroll
  for (int i = 0; i < 16; i++) {
    accA0[i] = 0.f; accA1[i] = 0.f; accB0[i] = 0.f; accB1[i] = 0.f;
    accLA[i] = 0.f; accLB[i] = 0.f;
  }
  apu onesf;
  onesf.u[0] = onesf.u[1] = onesf.u[2] = onesf.u[3] = 0x3F803F80u;  // bf16 1.0 x8

  int jmaxb = 15 - p;          // kv tiles (128 rows) needed by the heavy tile
  int srowK = lane >> 3, scolK = (lane & 7) << 3;
  int rowbK = w << 5;          // wave stages 32 K rows per tile
  int srowV = lane >> 4, scolV = (lane & 15) << 3;
  int rowbV = w << 4;          // wave stages 16 V rows (x128 t) per tile
  int swz = l31 & 7;

#define STAGE(kvt_, bi_) do {                                                        \
    int kv_ = (kvt_) << 7;                                                           \
    gload_lds16(Kh + (size_t)(kv_ + rowbK + srowK) * 64 + scolK,                     \
                &KL[bi_][rowbK << 6]);                                               \
    gload_lds16(Kh + (size_t)(kv_ + rowbK + 8 + srowK) * 64 + scolK,                 \
                &KL[bi_][(rowbK + 8) << 6]);                                         \
    gload_lds16(Kh + (size_t)(kv_ + rowbK + 16 + srowK) * 64 + scolK,                \
                &KL[bi_][(rowbK + 16) << 6]);                                        \
    gload_lds16(Kh + (size_t)(kv_ + rowbK + 24 + srowK) * 64 + scolK,                \
                &KL[bi_][(rowbK + 24) << 6]);                                        \
    gload_lds16(Vh + (size_t)(rowbV + srowV) * Tt + kv_ + scolV,                     \
                &VL[bi_][rowbV << 7]);                                               \
    gload_lds16(Vh + (size_t)(rowbV + 4 + srowV) * Tt + kv_ + scolV,                 \
                &VL[bi_][(rowbV + 4) << 7]);                                         \
    gload_lds16(Vh + (size_t)(rowbV + 8 + srowV) * Tt + kv_ + scolV,                 \
                &VL[bi_][(rowbV + 8) << 7]);                                         \
    gload_lds16(Vh + (size_t)(rowbV + 12 + srowV) * Tt + kv_ + scolV,                \
                &VL[bi_][(rowbV + 12) << 7]);                                        \
  } while (0)

  STAGE(0, 0);
  __syncthreads();

  int cur = 0;
  for (int jt = 0; jt <= jmaxb; ++jt) {
    if (jt < jmaxb) STAGE(jt + 1, cur ^ 1);  // latency hides under compute
    int base_kv = jt << 7;
    const unsigned short* KB = &KL[cur][0];
    const unsigned short* VB = &VL[cur][0];
#pragma unroll
    for (int n2 = 0; n2 < 4; n2++) {
      int relB = qgB - base_kv - (n2 << 5);   // heavy half, wave-uniform, mult 32
      int relA = qgA - base_kv - (n2 << 5);   // light half
      if (relB >= 0) {                        // heavy has unmasked rows
        bool doA = (relA >= 0);               // light not fully masked
        bf16x8 kf[4];
        int krowb = ((n2 << 5) + l31) << 6;
#pragma unroll
        for (int c = 0; c < 4; c++)
          kf[c] = *(const bf16x8*)(KB + krowb + ((((c << 1) + hi) ^ swz) << 3));
        f32x16 sA, sB;
#pragma unroll
        for (int i = 0; i < 16; i++) { sA[i] = 0.f; sB[i] = 0.f; }
        __builtin_amdgcn_s_setprio(1);
        if (doA) {
#pragma unroll
          for (int c = 0; c < 4; c++) {
            sA = MFMA32(kf[c], qfA[c], sA);
            sB = MFMA32(kf[c], qfB[c], sB);
          }
        } else {
#pragma unroll
          for (int c = 0; c < 4; c++) sB = MFMA32(kf[c], qfB[c], sB);
        }
        __builtin_amdgcn_s_setprio(0);
        float pA[16], pB[16];
        if (relB == 0) {       // heavy diagonal sub-block
          int rB = l31;
#pragma unroll
          for (int r = 0; r < 16; r++) {
            int krow = (r & 3) + ((r >> 2) << 3) + (hi << 2);
            pB[r] = EXP2(krow > rB ? -1e30f : sB[r]);
          }
        } else {
#pragma unroll
          for (int r = 0; r < 16; r++) pB[r] = EXP2(sB[r]);
        }
        if (doA) {
          if (relA == 0) {     // light diagonal sub-block
            int rA = l31;
#pragma unroll
            for (int r = 0; r < 16; r++) {
              int krow = (r & 3) + ((r >> 2) << 3) + (hi << 2);
              pA[r] = EXP2(krow > rA ? -1e30f : sA[r]);
            }
          } else {
#pragma unroll
            for (int r = 0; r < 16; r++) pA[r] = EXP2(sA[r]);
          }
        }
        vfu vf[2][2];
#pragma unroll
        for (int n2v = 0; n2v < 2; n2v++) {
          int vrowb = ((n2v << 5) + l31) << 7;   // V row stride = 128 t
#pragma unroll
          for (int cc = 0; cc < 2; cc++) {
            int blk0 = (n2 << 2) + (cc << 1);    // t-block in [0,15]
            vf[n2v][cc].u2[0] =
                *(const uint2*)(VB + vrowb + ((blk0 ^ swz) << 3) + (hi << 2));
            vf[n2v][cc].u2[1] =
                *(const uint2*)(VB + vrowb + (((blk0 + 1) ^ swz) << 3) + (hi << 2));
          }
        }
        apu b0, b1;
#pragma unroll
        for (int g = 0; g < 4; g++) {
          b0.u[g] = pk2(pB[2 * g], pB[2 * g + 1]);
          b1.u[g] = pk2(pB[8 + 2 * g], pB[8 + 2 * g + 1]);
        }
        __builtin_amdgcn_s_setprio(1);
        accB0 = MFMA32(b0.v, vf[0][0].v, accB0);
        accB1 = MFMA32(b0.v, vf[1][0].v, accB1);
        accLB = MFMA32(b0.v, onesf.v, accLB);
        accB0 = MFMA32(b1.v, vf[0][1].v, accB0);
        accB1 = MFMA32(b1.v, vf[1][1].v, accB1);
        accLB = MFMA32(b1.v, onesf.v, accLB);
        __builtin_amdgcn_s_setprio(0);
        if (doA) {
          apu a0, a1;
#pragma unroll
          for (int g = 0; g < 4; g++) {
            a0.u[g] = pk2(pA[2 * g], pA[2 * g + 1]);
            a1.u[g] = pk2(pA[8 + 2 * g], pA[8 + 2 * g + 1]);
          }
          __builtin_amdgcn_s_setprio(1);
          accA0 = MFMA32(a0.v, vf[0][0].v, accA0);
          accA1 = MFMA32(a0.v, vf[1][0].v, accA1);
          accLA = MFMA32(a0.v, onesf.v, accLA);
          accA0 = MFMA32(a1.v, vf[0][1].v, accA0);
          accA1 = MFMA32(a1.v, vf[1][1].v, accA1);
          accLA = MFMA32(a1.v, onesf.v, accLA);
          __builtin_amdgcn_s_setprio(0);
        }
      }
    }
    __syncthreads();
    cur ^= 1;
  }
#undef STAGE

  // accL[r] = lsum for q = crow(r,hi) -- same indexing as accA/accB rows.
  int bb = bh >> 4, hh = bh & 15;
#pragma unroll
  for (int r = 0; r < 16; r++) {
    int qr = (r & 3) + ((r >> 2) << 3) + (hi << 2);
    float invqA = 1.0f / accLA[r];
    float invqB = 1.0f / accLB[r];
    size_t baseA = ((size_t)(bb * Tt + qgA + qr)) * Dd + (hh << 6) + l31;
    size_t baseB = ((size_t)(bb * Tt + qgB + qr)) * Dd + (hh << 6) + l31;
    yb[baseA] = f2b(accA0[r] * invqA);
    yb[baseA + 32] = f2b(accA1[r] * invqA);
    yb[baseB] = f2b(accB0[r] * invqB);
    yb[baseB + 32] = f2b(accB1[r] * invqB);
  }
}

extern "C" void kernel_launch(void* const* d_in, const int* in_sizes, int n_in,
                              void* d_out, int out_size, void* d_ws, size_t ws_size,
                              hipStream_t stream) {
  const float* x = (const float*)d_in[0];
  const float* Wk = (const float*)d_in[1];
  const float* bk = (const float*)d_in[2];
  const float* Wq = (const float*)d_in[3];
  const float* bq = (const float*)d_in[4];
  const float* Wv = (const float*)d_in[5];
  const float* bv = (const float*)d_in[6];
  const float* Wp = (const float*)d_in[7];
  const float* bp = (const float*)d_in[8];
  float* out = (float*)d_out;

  char* ws = (char*)d_ws;
  unsigned short* xb  = (unsigned short*)(ws);                       // 16MB
  unsigned short* WkT = (unsigned short*)(ws + (16ull << 20));       // 2MB each
  unsigned short* WqT = (unsigned short*)(ws + (18ull << 20));
  unsigned short* WvT = (unsigned short*)(ws + (20ull << 20));
  unsigned short* WpT = (unsigned short*)(ws + (22ull << 20));
  unsigned short* Qb  = (unsigned short*)(ws + (24ull << 20));       // 16MB
  unsigned short* Kb  = (unsigned short*)(ws + (40ull << 20));       // 16MB
  unsigned short* VTb = (unsigned short*)(ws + (56ull << 20));       // 16MB
  unsigned short* yb  = (unsigned short*)(ws + (72ull << 20));       // 16MB (ends 88MB)

  k_front<<<8192, 256, 0, stream>>>(x, xb, Wk, Wq, Wv, Wp, WkT, WqT, WvT, WpT);
  k_gemm3<<<dim3(64, 8), 256, 0, stream>>>(xb, WqT, WkT, WvT, bq, bk, bv,
                                           Qb, Kb, VTb);
  k_attn<<<512, 256, 0, stream>>>(Qb, Kb, VTb, yb);
  k_gemm<<<dim3(64, 8), 256, 0, stream>>>(yb, WpT, bp, out);
}